// Round 4
// baseline (2268.399 us; speedup 1.0000x reference)
//
#include <hip/hip_runtime.h>
#include <hip/hip_bf16.h>

#define Bq   8
#define Tq   16
#define Nq   1024
#define Cq   48
#define Gq   32
#define Hq   150
#define H3q  450
#define TAq  32
#define OUTq 1024
#define BTq  128

#define NM_CAP 64    // m1 / m23 rows per (b,t): Binom(1024,.03) mean 30.7 sd 5.5
#define NA_CAP 192   // active (code|neighbor) rows: Binom(1024,.12) mean 123 sd 10.4

__device__ __forceinline__ float lrelu(float x){ return x > 0.f ? x : 0.01f * x; }
__device__ __forceinline__ float sigm(float x){ return 1.f / (1.f + expf(-x)); }

// -------- device-global scratch (everything read is written earlier in the same call) --------
__device__ int   g_n1[BTq], g_n23[BTq];
__device__ short g_list1[BTq][NM_CAP];
__device__ short g_list23[BTq][NM_CAP];        // row | (m2 ? 0x400 : 0), ascending row order
__device__ float g_Pc[Nq][Gq];                 // c_emb @ Wg
__device__ float g_Pn[Nq][Gq];                 // n_emb @ Wg
__device__ float g_codense[BTq][Nq][Gq];       // dense co (inactive rows = lrelu(bg))
__device__ float g_nodense[BTq][Nq][Gq];       // dense no (inactive rows = lrelu(bg))
__device__ float g_gi[BTq][NM_CAP][H3q];       // co@Wi+bi at m1 rows (slot = list1 index)
__device__ float g_vv[BTq][NM_CAP][Hq];        // qrows@Wv+bv at m23 rows
__device__ float g_hm23[BTq][NM_CAP][Hq];      // tanh(P@v) at m23 rows (t>=1)
__device__ float g_om23[BTq][Hq];
__device__ float g_hden[Bq][Nq][Hq];           // dense hidden state
__device__ float g_outs[BTq][Hq];

// -------- K_pre: project embeddings through Wg once (linear: (adj@ce)@Wg = adj@(ce@Wg)) --------
__global__ __launch_bounds__(256) void k_pre(const float* c_emb, const float* n_emb, const float* Wg){
    int idx   = blockIdx.x * 256 + threadIdx.x;   // 65536 threads exactly
    int which = idx >> 15;
    int r     = (idx >> 5) & 1023;
    int g     = idx & 31;
    const float* emb = which ? n_emb : c_emb;
    float acc = 0.f;
    for (int c = 0; c < Cq; ++c)
        acc += emb[r * Cq + c] * Wg[c * Gq + g];
    if (which) g_Pn[r][g] = acc; else g_Pc[r][g] = acc;
}

// -------- K_co: dense co/no per (b,t).
// co[m] = lrelu(c_m*(Pc[m]+agg_m) + bg), no[m] = lrelu(nb_m*(Pn[m]+agg_m) + bg),
// agg_m = sum_j adj[m][j]*(c_j*Pc[j] + nb_j*Pn[j])  (j restricted to active set) --------
__global__ __launch_bounds__(256) void k_co(const float* code_x, const float* neighbors,
                                            const float* adj, const float* bg){
    int bt = blockIdx.x, tid = threadIdx.x;
    __shared__ unsigned char c_s[Nq], nb_s[Nq];
    __shared__ short actj_s[NA_CAP];
    __shared__ int nact_s;
    for (int n = tid; n < Nq; n += 256){
        c_s[n]  = (code_x[bt * Nq + n]    > 0.f) ? 1 : 0;
        nb_s[n] = (neighbors[bt * Nq + n] > 0.f) ? 1 : 0;
    }
    __syncthreads();
    if (tid == 0){
        int c = 0;
        for (int n = 0; n < Nq; ++n)
            if ((c_s[n] | nb_s[n]) && c < NA_CAP) actj_s[c++] = (short)n;
        nact_s = c;
    }
    __syncthreads();
    int nact = nact_s;
    int g = tid & 31;
    float bgv = bg[g];
    for (int m = tid >> 5; m < Nq; m += 8){      // 8 groups of 32 lanes (lane = g)
        float agg = 0.f;
        if (c_s[m] | nb_s[m]){
            const float* arow = adj + (size_t)m * Nq;
            for (int jj = 0; jj < nact; ++jj){
                int j = actj_s[jj];
                float p = 0.f;
                if (c_s[j])  p += g_Pc[j][g];
                if (nb_s[j]) p += g_Pn[j][g];
                agg += arow[j] * p;
            }
        }
        float cm = c_s[m]  ? 1.f : 0.f;
        float nm = nb_s[m] ? 1.f : 0.f;
        g_codense[bt][m][g] = lrelu(cm * (g_Pc[m][g] + agg) + bgv);
        g_nodense[bt][m][g] = lrelu(nm * (g_Pn[m][g] + agg) + bgv);
    }
}

// -------- K_mid: lists (deterministic thread-0 scan), gi at m1 rows, attention at m23 rows --------
__global__ __launch_bounds__(512) void k_mid(const float* divided, const float* u_emb,
                                             const float* Wi, const float* bi,
                                             const float* Wk, const float* bk,
                                             const float* Wq_, const float* bq_,
                                             const float* Wv_, const float* bv_){
    int bt = blockIdx.x, tid = threadIdx.x;
    int t = bt % Tq, btp = bt - 1;
    __shared__ unsigned char f1_s[Nq], f23_s[Nq];   // f23: 0=no, 1=m2, 2=m3
    __shared__ short l1_s[NM_CAP], l23_s[NM_CAP];
    __shared__ int n1_s, n23_s;
    __shared__ float co1_s[NM_CAP][Gq];
    __shared__ float qr_s[NM_CAP][Gq];
    __shared__ float q_s[NM_CAP][TAq];
    __shared__ float k_s[NM_CAP][TAq];
    __shared__ float s_s[NM_CAP][NM_CAP];

    for (int n = tid; n < Nq; n += 512){
        const float* d = divided + ((size_t)bt * Nq + n) * 3;
        f1_s[n] = (d[0] > 0.f) ? 1 : 0;
        f23_s[n] = (d[1] > 0.f) ? 1 : ((d[2] > 0.f) ? 2 : 0);
    }
    __syncthreads();
    if (tid == 0){
        int c1 = 0, c23 = 0;
        for (int n = 0; n < Nq; ++n){
            if (f1_s[n]  && c1  < NM_CAP) l1_s[c1++]   = (short)n;
            if (f23_s[n] && c23 < NM_CAP) l23_s[c23++] = (short)(n | (f23_s[n] == 1 ? 0x400 : 0));
        }
        n1_s = c1; n23_s = c23;
        g_n1[bt] = c1; g_n23[bt] = c23;
    }
    __syncthreads();
    int n1 = n1_s, n23 = n23_s;
    for (int i = tid; i < n1;  i += 512) g_list1[bt][i]  = l1_s[i];
    for (int i = tid; i < n23; i += 512) g_list23[bt][i] = l23_s[i];
    for (int idx = tid; idx < n1 * Gq; idx += 512){
        int i = idx >> 5, g = idx & 31;
        co1_s[i][g] = g_codense[bt][l1_s[i]][g];
    }
    __syncthreads();

    // gi = co@Wi + bi at m1 rows (thread per output column)
    if (tid < H3q){
        int j = tid;
        float bij = bi[j];
        for (int i = 0; i < n1; ++i){
            float acc = bij;
            for (int g = 0; g < Gq; ++g) acc += co1_s[i][g] * Wi[g * H3q + j];
            g_gi[bt][i][j] = acc;
        }
    }
    if (t == 0 || n23 == 0) return;   // block-uniform; attention applies only at t>=1

    // qrows: m2 -> no(t-1)[row] (dense, exact for inactive rows too); m3 -> u_emb[row]
    for (int idx = tid; idx < n23 * Gq; idx += 512){
        int i = idx >> 5, g = idx & 31;
        int e = l23_s[i], row = e & 1023;
        qr_s[i][g] = (e & 0x400) ? g_nodense[btp][row][g] : u_emb[row * Gq + g];
    }
    __syncthreads();
    // k = co@Wk+bk (keys), q = qrows@Wq+bq, v = qrows@Wv+bv
    for (int idx = tid; idx < n23 * TAq; idx += 512){
        int i = idx >> 5, a = idx & 31;
        int row = l23_s[i] & 1023;
        float acck = bk[a], accq = bq_[a];
        for (int g = 0; g < Gq; ++g){
            acck += g_codense[bt][row][g] * Wk[g * TAq + a];
            accq += qr_s[i][g] * Wq_[g * TAq + a];
        }
        k_s[i][a] = acck; q_s[i][a] = accq;
    }
    for (int idx = tid; idx < n23 * Hq; idx += 512){
        int i = idx / Hq, h = idx % Hq;
        float acc = bv_[h];
        for (int g = 0; g < Gq; ++g) acc += qr_s[i][g] * Wv_[g * Hq + h];
        g_vv[bt][i][h] = acc;
    }
    __syncthreads();

    const float scale = 0.17677669529663687f;   // 1/sqrt(32)
    for (int idx = tid; idx < n23 * n23; idx += 512){
        int i = idx / n23, j = idx % n23;
        float acc = 0.f;
        for (int a = 0; a < TAq; ++a) acc += q_s[i][a] * k_s[j][a];
        s_s[i][j] = acc * scale;
    }
    __syncthreads();
    for (int i = tid; i < n23; i += 512){        // per-query softmax over the m23 key set
        float mx = -1e30f;
        for (int j = 0; j < n23; ++j) mx = fmaxf(mx, s_s[i][j]);
        float sum = 0.f;
        for (int j = 0; j < n23; ++j){ float e = expf(s_s[i][j] - mx); s_s[i][j] = e; sum += e; }
        float inv = 1.f / sum;
        for (int j = 0; j < n23; ++j) s_s[i][j] *= inv;
    }
    __syncthreads();
    for (int idx = tid; idx < n23 * Hq; idx += 512){
        int i = idx / Hq, h = idx % Hq;
        float acc = 0.f;
        for (int j = 0; j < n23; ++j) acc += s_s[i][j] * g_vv[bt][j][h];
        g_hm23[bt][i][h] = tanhf(acc);
    }
    __syncthreads();
    for (int h = tid; h < Hq; h += 512){
        float mx = -1e30f;
        for (int i = 0; i < n23; ++i) mx = fmaxf(mx, g_hm23[bt][i][h]);
        g_om23[bt][h] = mx;
    }
}

// -------- K_seq: the only true time recurrence (GRU). Dense h state; activity from input masks --------
__global__ __launch_bounds__(512) void k_seq(const float* divided, const float* Wh, const float* bh){
    int b = blockIdx.x, tid = threadIdx.x;
    __shared__ float hm1_s[NM_CAP][Hq];          // 38.4 KB
    __shared__ short l1_s[NM_CAP], l23_s[NM_CAP], lp_s[2 * NM_CAP];
    __shared__ unsigned char ap_s[NM_CAP];
    __shared__ int npv_s;
    for (int idx = tid; idx < Nq * Hq; idx += 512) (&g_hden[b][0][0])[idx] = 0.f;
    if (tid == 0) npv_s = 0;
    __syncthreads();

    for (int t = 0; t < Tq; ++t){
        int bt = b * Tq + t;
        int n1  = g_n1[bt];
        int n23 = (t > 0) ? g_n23[bt] : 0;
        for (int i = tid; i < n1;  i += 512) l1_s[i]  = g_list1[bt][i];
        for (int i = tid; i < n23; i += 512) l23_s[i] = (short)(g_list23[bt][i] & 1023);
        __syncthreads();

        // h_prev[row] nonzero iff row active at t-1 (m1, or m23 when t-1>0) — straight from input masks
        for (int i = tid; i < n1; i += 512){
            int row = l1_s[i];
            unsigned char ap = 0;
            if (t > 0){
                const float* d = divided + ((size_t)(bt - 1) * Nq + row) * 3;
                if (d[0] > 0.f) ap = 1;
                else if (t > 1 && (d[1] > 0.f || d[2] > 0.f)) ap = 1;
            }
            ap_s[i] = ap;
        }
        __syncthreads();

        // GRU at m1 rows; gh matvec only where h_prev != 0 (~2 rows/step)
        for (int idx = tid; idx < n1 * Hq; idx += 512){
            int i = idx / Hq, h = idx % Hq;
            float ghr = bh[h], ghz = bh[Hq + h], ghn = bh[2 * Hq + h];
            float hp = 0.f;
            if (ap_s[i]){
                const float* hb = g_hden[b][l1_s[i]];
                for (int k2 = 0; k2 < Hq; ++k2){
                    float hv = hb[k2];
                    const float* wr = Wh + (size_t)k2 * H3q;
                    ghr += hv * wr[h];
                    ghz += hv * wr[Hq + h];
                    ghn += hv * wr[2 * Hq + h];
                }
                hp = hb[h];
            }
            float ir = g_gi[bt][i][h], iz = g_gi[bt][i][Hq + h], ig = g_gi[bt][i][2 * Hq + h];
            float r  = sigm(ir + ghr);
            float z  = sigm(iz + ghz);
            float ng = tanhf(ig + r * ghn);
            hm1_s[i][h] = (1.f - z) * ng + z * hp;
        }
        __syncthreads();

        // zero rows active at t-1, then write rows active at t
        int npv = npv_s;
        for (int idx = tid; idx < npv * Hq; idx += 512){
            int i = idx / Hq, h = idx % Hq;
            g_hden[b][lp_s[i]][h] = 0.f;
        }
        __syncthreads();
        for (int idx = tid; idx < n1 * Hq; idx += 512){
            int i = idx / Hq, h = idx % Hq;
            g_hden[b][l1_s[i]][h] = hm1_s[i][h];
        }
        for (int idx = tid; idx < n23 * Hq; idx += 512){
            int i = idx / Hq, h = idx % Hq;
            g_hden[b][l23_s[i]][h] = g_hm23[bt][i][h];
        }
        // outs[b,t] = om1 + om23
        for (int h = tid; h < Hq; h += 512){
            float o = 0.f;
            if (n1 > 0){
                float mx = -1e30f;
                for (int i = 0; i < n1; ++i) mx = fmaxf(mx, hm1_s[i][h]);
                o = mx;
            }
            if (n23 > 0) o += g_om23[bt][h];
            g_outs[bt][h] = o;
        }
        for (int i = tid; i < n1;  i += 512) lp_s[i]      = l1_s[i];
        for (int i = tid; i < n23; i += 512) lp_s[n1 + i] = l23_s[i];
        if (tid == 0) npv_s = n1 + n23;
        __syncthreads();
    }
}

// -------- K_final: temporal attention + classifier --------
__global__ __launch_bounds__(256) void k_final(const int* lens, const float* Wd, const float* bd,
                                               const float* ctx, const float* Wc, const float* bc,
                                               float* out){
    int b = blockIdx.x, tid = threadIdx.x;
    __shared__ float outs_s[Tq][Hq];
    __shared__ float wdc_s[Hq];
    __shared__ float score_s[Tq];
    __shared__ float pooled_s[Hq];
    for (int idx = tid; idx < Tq * Hq; idx += 256){
        int t = idx / Hq, h = idx % Hq;
        outs_s[t][h] = g_outs[b * Tq + t][h];
    }
    for (int h = tid; h < Hq; h += 256){
        float acc = 0.f;
        for (int d = 0; d < 32; ++d) acc += Wd[h * 32 + d] * ctx[d];
        wdc_s[h] = acc;
    }
    __syncthreads();
    int len = lens[b];
    if (tid < Tq){
        int t = tid;
        float acc = 0.f;
        for (int d = 0; d < 32; ++d) acc += bd[d] * ctx[d];
        for (int h = 0; h < Hq; ++h) acc += outs_s[t][h] * wdc_s[h];
        score_s[t] = (t < len) ? acc : -1e30f;
    }
    __syncthreads();
    if (tid == 0){
        float mx = -1e30f;
        for (int t = 0; t < Tq; ++t) mx = fmaxf(mx, score_s[t]);
        float sum = 0.f;
        for (int t = 0; t < Tq; ++t){ float e = expf(score_s[t] - mx); score_s[t] = e; sum += e; }
        float inv = 1.f / sum;
        for (int t = 0; t < Tq; ++t) score_s[t] *= inv;
    }
    __syncthreads();
    for (int h = tid; h < Hq; h += 256){
        float acc = 0.f;
        for (int t = 0; t < Tq; ++t) acc += score_s[t] * outs_s[t][h];
        pooled_s[h] = acc;
    }
    __syncthreads();
    for (int o = tid; o < OUTq; o += 256){
        float acc = bc[o];
        for (int h = 0; h < Hq; ++h) acc += pooled_s[h] * Wc[h * OUTq + o];
        out[b * OUTq + o] = sigm(acc);
    }
}

extern "C" void kernel_launch(void* const* d_in, const int* in_sizes, int n_in,
                              void* d_out, int out_size, void* d_ws, size_t ws_size,
                              hipStream_t stream){
    const float* code_x    = (const float*)d_in[0];
    const float* divided   = (const float*)d_in[1];
    const float* neighbors = (const float*)d_in[2];
    const int*   lens      = (const int*)  d_in[3];
    const float* adj       = (const float*)d_in[4];
    const float* c_emb     = (const float*)d_in[5];
    const float* n_emb     = (const float*)d_in[6];
    const float* u_emb     = (const float*)d_in[7];
    const float* Wg        = (const float*)d_in[8];
    const float* bg        = (const float*)d_in[9];
    const float* Wi        = (const float*)d_in[10];
    const float* bi        = (const float*)d_in[11];
    const float* Wh        = (const float*)d_in[12];
    const float* bh        = (const float*)d_in[13];
    const float* Wq_       = (const float*)d_in[14];
    const float* bq_       = (const float*)d_in[15];
    const float* Wk_       = (const float*)d_in[16];
    const float* bk_       = (const float*)d_in[17];
    const float* Wv_       = (const float*)d_in[18];
    const float* bv_       = (const float*)d_in[19];
    const float* Wd_       = (const float*)d_in[20];
    const float* bd_       = (const float*)d_in[21];
    const float* ctx       = (const float*)d_in[22];
    const float* Wc_       = (const float*)d_in[23];
    const float* bc_       = (const float*)d_in[24];
    float* out = (float*)d_out;

    hipLaunchKernelGGL(k_pre,   dim3(256), dim3(256), 0, stream, c_emb, n_emb, Wg);
    hipLaunchKernelGGL(k_co,    dim3(BTq), dim3(256), 0, stream, code_x, neighbors, adj, bg);
    hipLaunchKernelGGL(k_mid,   dim3(BTq), dim3(512), 0, stream, divided, u_emb,
                       Wi, bi, Wk_, bk_, Wq_, bq_, Wv_, bv_);
    hipLaunchKernelGGL(k_seq,   dim3(Bq),  dim3(512), 0, stream, divided, Wh, bh);
    hipLaunchKernelGGL(k_final, dim3(Bq),  dim3(256), 0, stream, lens, Wd_, bd_, ctx, Wc_, bc_, out);
}

// Round 5
// 725.196 us; speedup vs baseline: 3.1280x; 3.1280x over previous
//
#include <hip/hip_runtime.h>
#include <hip/hip_bf16.h>

#define Bq   8
#define Tq   16
#define Nq   1024
#define Cq   48
#define Gq   32
#define Hq   150
#define H3q  450
#define TAq  32
#define OUTq 1024
#define BTq  128

#define NC_CAP 128   // active code / neighbor rows per (b,t): Binom(1024,.06) mean 61 sd 7.6
#define NM_CAP 64    // m1 / m23 rows per (b,t): Binom(1024,.03) mean 30.7 sd 5.5

__device__ __forceinline__ float lrelu(float x){ return x > 0.f ? x : 0.01f * x; }
__device__ __forceinline__ float sigm(float x){ return 1.f / (1.f + expf(-x)); }

// -------- device-global scratch (everything read is written earlier in the same call) --------
__device__ int   g_n1[BTq], g_n23[BTq];
__device__ short g_list1[BTq][NM_CAP];
__device__ short g_list23[BTq][NM_CAP];        // row | (m2 ? 0x400 : 0), ascending row order
__device__ short g_mapc[BTq][Nq];              // row -> slot in c-list (-1 if inactive)
__device__ short g_mapn[BTq][Nq];              // row -> slot in nb-list (-1 if inactive)
__device__ float g_Pc[Nq][Gq];                 // c_emb @ Wg
__device__ float g_Pn[Nq][Gq];                 // n_emb @ Wg
__device__ float g_co[BTq][NC_CAP][Gq];        // co at active c rows (slot order)
__device__ float g_no[BTq][NC_CAP][Gq];        // no at active nb rows (slot order)
__device__ float g_gi[BTq][NM_CAP][H3q];       // co@Wi+bi at m1 rows (slot = list1 index)
__device__ float g_vv[BTq][NM_CAP][Hq];        // qrows@Wv+bv at m23 rows
__device__ float g_hm23[BTq][NM_CAP][Hq];      // tanh(P@v) at m23 rows (t>=1)
__device__ float g_om23[BTq][Hq];
__device__ float g_hden[Bq][Nq][Hq];           // dense hidden state
__device__ float g_outs[BTq][Hq];

// -------- K_pre: project embeddings through Wg once (linear: (adj@ce)@Wg = adj@(ce@Wg)) --------
__global__ __launch_bounds__(256) void k_pre(const float* c_emb, const float* n_emb, const float* Wg){
    int idx   = blockIdx.x * 256 + threadIdx.x;   // 65536 threads exactly
    int which = idx >> 15;
    int r     = (idx >> 5) & 1023;
    int g     = idx & 31;
    const float* emb = which ? n_emb : c_emb;
    float acc = 0.f;
    for (int c = 0; c < Cq; ++c)
        acc += emb[r * Cq + c] * Wg[c * Gq + g];
    if (which) g_Pn[r][g] = acc; else g_Pc[r][g] = acc;
}

// -------- K_co: sparse co/no at active rows only. Deterministic ballot compaction. --------
// co[m] = lrelu(Pc[m] + agg_m + bg) at c-active m;  no[m] = lrelu(Pn[m] + agg_m + bg) at nb-active m;
// agg_m = sum_j adj[m][j] * (c_j*Pc[j] + nb_j*Pn[j])   (c/nb sets are disjoint by construction)
__global__ __launch_bounds__(512) void k_co(const float* code_x, const float* neighbors,
                                            const float* adj, const float* bg){
    int bt = blockIdx.x, tid = threadIdx.x;
    __shared__ short lc_s[NC_CAP], ln_s[NC_CAP];
    __shared__ int nc_s, nn_s;
    __shared__ float Pca_s[NC_CAP][Gq];   // 16 KB
    __shared__ float Pna_s[NC_CAP][Gq];   // 16 KB
    int wave = tid >> 6, lane = tid & 63;

    if (wave == 0){           // compact c-active rows (deterministic, ascending)
        int base = 0;
        for (int start = 0; start < Nq; start += 64){
            int n = start + lane;
            int pred = code_x[bt * Nq + n] > 0.f;
            unsigned long long mm = __ballot(pred);
            int pos = base + (int)__popcll(mm & ((1ull << lane) - 1ull));
            if (pred && pos < NC_CAP) lc_s[pos] = (short)n;
            base += (int)__popcll(mm);
        }
        if (lane == 0) nc_s = min(base, NC_CAP);
    } else if (wave == 1){    // compact nb-active rows
        int base = 0;
        for (int start = 0; start < Nq; start += 64){
            int n = start + lane;
            int pred = neighbors[bt * Nq + n] > 0.f;
            unsigned long long mm = __ballot(pred);
            int pos = base + (int)__popcll(mm & ((1ull << lane) - 1ull));
            if (pred && pos < NC_CAP) ln_s[pos] = (short)n;
            base += (int)__popcll(mm);
        }
        if (lane == 0) nn_s = min(base, NC_CAP);
    }
    for (int n = tid; n < Nq; n += 512){ g_mapc[bt][n] = -1; g_mapn[bt][n] = -1; }
    __syncthreads();
    int nc = nc_s, nn = nn_s;
    for (int i = tid; i < nc; i += 512) g_mapc[bt][lc_s[i]] = (short)i;
    for (int i = tid; i < nn; i += 512) g_mapn[bt][ln_s[i]] = (short)i;
    for (int idx = tid; idx < nc * Gq; idx += 512){
        int i = idx >> 5, g = idx & 31;
        Pca_s[i][g] = g_Pc[lc_s[i]][g];
    }
    for (int idx = tid; idx < nn * Gq; idx += 512){
        int i = idx >> 5, g = idx & 31;
        Pna_s[i][g] = g_Pn[ln_s[i]][g];
    }
    __syncthreads();

    int g = tid & 31;
    float bgv = bg[g];
    int total = nc + nn;
    for (int r = tid >> 5; r < total; r += 16){   // 16 groups of 32 lanes (lane = g)
        int isC = (r < nc) ? 1 : 0;
        int m = isC ? (int)lc_s[r] : (int)ln_s[r - nc];
        const float* arow = adj + (size_t)m * Nq;
        float agg = 0.f;
        #pragma unroll 4
        for (int j = 0; j < nc; ++j) agg += arow[lc_s[j]] * Pca_s[j][g];
        #pragma unroll 4
        for (int j = 0; j < nn; ++j) agg += arow[ln_s[j]] * Pna_s[j][g];
        if (isC) g_co[bt][r][g]      = lrelu(Pca_s[r][g]      + agg + bgv);
        else     g_no[bt][r - nc][g] = lrelu(Pna_s[r - nc][g] + agg + bgv);
    }
}

// -------- K_mid: lists (ballot compaction), gi at m1 rows, attention at m23 rows --------
__global__ __launch_bounds__(512) void k_mid(const float* divided, const float* u_emb,
                                             const float* Wi, const float* bi,
                                             const float* Wk, const float* bk,
                                             const float* Wq_, const float* bq_,
                                             const float* Wv_, const float* bv_,
                                             const float* bg){
    int bt = blockIdx.x, tid = threadIdx.x;
    int t = bt % Tq, btp = bt - 1;
    __shared__ short l1_s[NM_CAP], l23_s[NM_CAP];
    __shared__ int n1_s, n23_s;
    __shared__ float co1_s[NM_CAP][Gq];
    __shared__ float co23_s[NM_CAP][Gq];
    __shared__ float qr_s[NM_CAP][Gq];
    __shared__ float q_s[NM_CAP][TAq];
    __shared__ float k_s[NM_CAP][TAq];
    __shared__ float s_s[NM_CAP][NM_CAP];
    int wave = tid >> 6, lane = tid & 63;

    if (wave == 0){           // m1 list
        int base = 0;
        for (int start = 0; start < Nq; start += 64){
            int n = start + lane;
            int pred = divided[((size_t)bt * Nq + n) * 3 + 0] > 0.f;
            unsigned long long mm = __ballot(pred);
            int pos = base + (int)__popcll(mm & ((1ull << lane) - 1ull));
            if (pred && pos < NM_CAP) l1_s[pos] = (short)n;
            base += (int)__popcll(mm);
        }
        if (lane == 0) n1_s = min(base, NM_CAP);
    } else if (wave == 1){    // m23 list with m2 tag
        int base = 0;
        for (int start = 0; start < Nq; start += 64){
            int n = start + lane;
            float m2 = divided[((size_t)bt * Nq + n) * 3 + 1];
            float m3 = divided[((size_t)bt * Nq + n) * 3 + 2];
            int pred = (m2 > 0.f) || (m3 > 0.f);
            unsigned long long mm = __ballot(pred);
            int pos = base + (int)__popcll(mm & ((1ull << lane) - 1ull));
            if (pred && pos < NM_CAP) l23_s[pos] = (short)(n | (m2 > 0.f ? 0x400 : 0));
            base += (int)__popcll(mm);
        }
        if (lane == 0) n23_s = min(base, NM_CAP);
    }
    __syncthreads();
    int n1 = n1_s, n23 = n23_s;
    for (int i = tid; i < n1;  i += 512) g_list1[bt][i]  = l1_s[i];
    for (int i = tid; i < n23; i += 512) g_list23[bt][i] = l23_s[i];
    if (tid == 0){ g_n1[bt] = n1; g_n23[bt] = n23; }
    // stage co rows (m1|m2|m3 => code_x active => mapc >= 0 guaranteed)
    for (int idx = tid; idx < n1 * Gq; idx += 512){
        int i = idx >> 5, g = idx & 31;
        co1_s[i][g] = g_co[bt][g_mapc[bt][l1_s[i]]][g];
    }
    for (int idx = tid; idx < n23 * Gq; idx += 512){
        int i = idx >> 5, g = idx & 31;
        co23_s[i][g] = g_co[bt][g_mapc[bt][l23_s[i] & 1023]][g];
    }
    __syncthreads();

    // gi = co@Wi + bi at m1 rows (thread per output column, Wi column in registers)
    if (tid < H3q){
        float wcol[Gq];
        #pragma unroll
        for (int g = 0; g < Gq; ++g) wcol[g] = Wi[g * H3q + tid];
        float bij = bi[tid];
        for (int i = 0; i < n1; ++i){
            float acc = bij;
            #pragma unroll
            for (int g = 0; g < Gq; ++g) acc += co1_s[i][g] * wcol[g];
            g_gi[bt][i][tid] = acc;
        }
    }
    if (t == 0 || n23 == 0) return;   // block-uniform; attention applies only at t>=1

    // qrows: m2 -> no(t-1)[row]; inactive nb rows at t-1 have exact value lrelu(bg). m3 -> u_emb[row]
    for (int idx = tid; idx < n23 * Gq; idx += 512){
        int i = idx >> 5, g = idx & 31;
        int e = l23_s[i], row = e & 1023;
        float qv;
        if (e & 0x400){
            int slot = g_mapn[btp][row];
            qv = (slot >= 0) ? g_no[btp][slot][g] : lrelu(bg[g]);
        } else {
            qv = u_emb[row * Gq + g];
        }
        qr_s[i][g] = qv;
    }
    __syncthreads();
    // k = co@Wk+bk (keys), q = qrows@Wq+bq, v = qrows@Wv+bv
    for (int idx = tid; idx < n23 * TAq; idx += 512){
        int i = idx >> 5, a = idx & 31;
        float acck = bk[a], accq = bq_[a];
        #pragma unroll
        for (int g = 0; g < Gq; ++g){
            acck += co23_s[i][g] * Wk[g * TAq + a];
            accq += qr_s[i][g] * Wq_[g * TAq + a];
        }
        k_s[i][a] = acck; q_s[i][a] = accq;
    }
    for (int idx = tid; idx < n23 * Hq; idx += 512){
        int i = idx / Hq, h = idx % Hq;
        float acc = bv_[h];
        #pragma unroll
        for (int g = 0; g < Gq; ++g) acc += qr_s[i][g] * Wv_[g * Hq + h];
        g_vv[bt][i][h] = acc;
    }
    __syncthreads();

    const float scale = 0.17677669529663687f;   // 1/sqrt(32)
    for (int idx = tid; idx < n23 * n23; idx += 512){
        int i = idx / n23, j = idx % n23;
        float acc = 0.f;
        #pragma unroll
        for (int a = 0; a < TAq; ++a) acc += q_s[i][a] * k_s[j][a];
        s_s[i][j] = acc * scale;
    }
    __syncthreads();
    for (int i = tid; i < n23; i += 512){        // per-query softmax over the m23 key set
        float mx = -1e30f;
        for (int j = 0; j < n23; ++j) mx = fmaxf(mx, s_s[i][j]);
        float sum = 0.f;
        for (int j = 0; j < n23; ++j){ float e = expf(s_s[i][j] - mx); s_s[i][j] = e; sum += e; }
        float inv = 1.f / sum;
        for (int j = 0; j < n23; ++j) s_s[i][j] *= inv;
    }
    __syncthreads();
    for (int idx = tid; idx < n23 * Hq; idx += 512){
        int i = idx / Hq, h = idx % Hq;
        float acc = 0.f;
        for (int j = 0; j < n23; ++j) acc += s_s[i][j] * g_vv[bt][j][h];
        g_hm23[bt][i][h] = tanhf(acc);
    }
    __syncthreads();
    for (int h = tid; h < Hq; h += 512){
        float mx = -1e30f;
        for (int i = 0; i < n23; ++i) mx = fmaxf(mx, g_hm23[bt][i][h]);
        g_om23[bt][h] = mx;
    }
}

// -------- K_seq: the only true time recurrence (GRU). Dense h state; activity from input masks --------
__global__ __launch_bounds__(512) void k_seq(const float* divided, const float* Wh, const float* bh){
    int b = blockIdx.x, tid = threadIdx.x;
    __shared__ float hm1_s[NM_CAP][Hq];          // 38.4 KB
    __shared__ short l1_s[NM_CAP], l23_s[NM_CAP], lp_s[2 * NM_CAP];
    __shared__ unsigned char ap_s[NM_CAP];
    __shared__ int npv_s;
    for (int idx = tid; idx < Nq * Hq; idx += 512) (&g_hden[b][0][0])[idx] = 0.f;
    if (tid == 0) npv_s = 0;
    __syncthreads();

    for (int t = 0; t < Tq; ++t){
        int bt = b * Tq + t;
        int n1  = g_n1[bt];
        int n23 = (t > 0) ? g_n23[bt] : 0;
        for (int i = tid; i < n1;  i += 512) l1_s[i]  = g_list1[bt][i];
        for (int i = tid; i < n23; i += 512) l23_s[i] = (short)(g_list23[bt][i] & 1023);
        __syncthreads();

        // h_prev[row] nonzero iff row active at t-1 (m1, or m23 when t-1>0) — straight from input masks
        for (int i = tid; i < n1; i += 512){
            int row = l1_s[i];
            unsigned char ap = 0;
            if (t > 0){
                const float* d = divided + ((size_t)(bt - 1) * Nq + row) * 3;
                if (d[0] > 0.f) ap = 1;
                else if (t > 1 && (d[1] > 0.f || d[2] > 0.f)) ap = 1;
            }
            ap_s[i] = ap;
        }
        __syncthreads();

        // GRU at m1 rows; gh matvec only where h_prev != 0 (~2 rows/step)
        for (int idx = tid; idx < n1 * Hq; idx += 512){
            int i = idx / Hq, h = idx % Hq;
            float ghr = bh[h], ghz = bh[Hq + h], ghn = bh[2 * Hq + h];
            float hp = 0.f;
            if (ap_s[i]){
                const float* hb = g_hden[b][l1_s[i]];
                for (int k2 = 0; k2 < Hq; ++k2){
                    float hv = hb[k2];
                    const float* wr = Wh + (size_t)k2 * H3q;
                    ghr += hv * wr[h];
                    ghz += hv * wr[Hq + h];
                    ghn += hv * wr[2 * Hq + h];
                }
                hp = hb[h];
            }
            float ir = g_gi[bt][i][h], iz = g_gi[bt][i][Hq + h], ig = g_gi[bt][i][2 * Hq + h];
            float r  = sigm(ir + ghr);
            float z  = sigm(iz + ghz);
            float ng = tanhf(ig + r * ghn);
            hm1_s[i][h] = (1.f - z) * ng + z * hp;
        }
        __syncthreads();

        // zero rows active at t-1, then write rows active at t
        int npv = npv_s;
        for (int idx = tid; idx < npv * Hq; idx += 512){
            int i = idx / Hq, h = idx % Hq;
            g_hden[b][lp_s[i]][h] = 0.f;
        }
        __syncthreads();
        for (int idx = tid; idx < n1 * Hq; idx += 512){
            int i = idx / Hq, h = idx % Hq;
            g_hden[b][l1_s[i]][h] = hm1_s[i][h];
        }
        for (int idx = tid; idx < n23 * Hq; idx += 512){
            int i = idx / Hq, h = idx % Hq;
            g_hden[b][l23_s[i]][h] = g_hm23[bt][i][h];
        }
        // outs[b,t] = om1 + om23
        for (int h = tid; h < Hq; h += 512){
            float o = 0.f;
            if (n1 > 0){
                float mx = -1e30f;
                for (int i = 0; i < n1; ++i) mx = fmaxf(mx, hm1_s[i][h]);
                o = mx;
            }
            if (n23 > 0) o += g_om23[bt][h];
            g_outs[bt][h] = o;
        }
        for (int i = tid; i < n1;  i += 512) lp_s[i]      = l1_s[i];
        for (int i = tid; i < n23; i += 512) lp_s[n1 + i] = l23_s[i];
        if (tid == 0) npv_s = n1 + n23;
        __syncthreads();
    }
}

// -------- K_final: temporal attention + classifier --------
__global__ __launch_bounds__(256) void k_final(const int* lens, const float* Wd, const float* bd,
                                               const float* ctx, const float* Wc, const float* bc,
                                               float* out){
    int b = blockIdx.x, tid = threadIdx.x;
    __shared__ float outs_s[Tq][Hq];
    __shared__ float wdc_s[Hq];
    __shared__ float score_s[Tq];
    __shared__ float pooled_s[Hq];
    for (int idx = tid; idx < Tq * Hq; idx += 256){
        int t = idx / Hq, h = idx % Hq;
        outs_s[t][h] = g_outs[b * Tq + t][h];
    }
    for (int h = tid; h < Hq; h += 256){
        float acc = 0.f;
        for (int d = 0; d < 32; ++d) acc += Wd[h * 32 + d] * ctx[d];
        wdc_s[h] = acc;
    }
    __syncthreads();
    int len = lens[b];
    if (tid < Tq){
        int t = tid;
        float acc = 0.f;
        for (int d = 0; d < 32; ++d) acc += bd[d] * ctx[d];
        for (int h = 0; h < Hq; ++h) acc += outs_s[t][h] * wdc_s[h];
        score_s[t] = (t < len) ? acc : -1e30f;
    }
    __syncthreads();
    if (tid == 0){
        float mx = -1e30f;
        for (int t = 0; t < Tq; ++t) mx = fmaxf(mx, score_s[t]);
        float sum = 0.f;
        for (int t = 0; t < Tq; ++t){ float e = expf(score_s[t] - mx); score_s[t] = e; sum += e; }
        float inv = 1.f / sum;
        for (int t = 0; t < Tq; ++t) score_s[t] *= inv;
    }
    __syncthreads();
    for (int h = tid; h < Hq; h += 256){
        float acc = 0.f;
        for (int t = 0; t < Tq; ++t) acc += score_s[t] * outs_s[t][h];
        pooled_s[h] = acc;
    }
    __syncthreads();
    for (int o = tid; o < OUTq; o += 256){
        float acc = bc[o];
        for (int h = 0; h < Hq; ++h) acc += pooled_s[h] * Wc[h * OUTq + o];
        out[b * OUTq + o] = sigm(acc);
    }
}

extern "C" void kernel_launch(void* const* d_in, const int* in_sizes, int n_in,
                              void* d_out, int out_size, void* d_ws, size_t ws_size,
                              hipStream_t stream){
    const float* code_x    = (const float*)d_in[0];
    const float* divided   = (const float*)d_in[1];
    const float* neighbors = (const float*)d_in[2];
    const int*   lens      = (const int*)  d_in[3];
    const float* adj       = (const float*)d_in[4];
    const float* c_emb     = (const float*)d_in[5];
    const float* n_emb     = (const float*)d_in[6];
    const float* u_emb     = (const float*)d_in[7];
    const float* Wg        = (const float*)d_in[8];
    const float* bg        = (const float*)d_in[9];
    const float* Wi        = (const float*)d_in[10];
    const float* bi        = (const float*)d_in[11];
    const float* Wh        = (const float*)d_in[12];
    const float* bh        = (const float*)d_in[13];
    const float* Wq_       = (const float*)d_in[14];
    const float* bq_       = (const float*)d_in[15];
    const float* Wk_       = (const float*)d_in[16];
    const float* bk_       = (const float*)d_in[17];
    const float* Wv_       = (const float*)d_in[18];
    const float* bv_       = (const float*)d_in[19];
    const float* Wd_       = (const float*)d_in[20];
    const float* bd_       = (const float*)d_in[21];
    const float* ctx       = (const float*)d_in[22];
    const float* Wc_       = (const float*)d_in[23];
    const float* bc_       = (const float*)d_in[24];
    float* out = (float*)d_out;

    hipLaunchKernelGGL(k_pre,   dim3(256), dim3(256), 0, stream, c_emb, n_emb, Wg);
    hipLaunchKernelGGL(k_co,    dim3(BTq), dim3(512), 0, stream, code_x, neighbors, adj, bg);
    hipLaunchKernelGGL(k_mid,   dim3(BTq), dim3(512), 0, stream, divided, u_emb,
                       Wi, bi, Wk_, bk_, Wq_, bq_, Wv_, bv_, bg);
    hipLaunchKernelGGL(k_seq,   dim3(Bq),  dim3(512), 0, stream, divided, Wh, bh);
    hipLaunchKernelGGL(k_final, dim3(Bq),  dim3(256), 0, stream, lens, Wd_, bd_, ctx, Wc_, bc_, out);
}

// Round 6
// 449.608 us; speedup vs baseline: 5.0453x; 1.6130x over previous
//
#include <hip/hip_runtime.h>
#include <hip/hip_bf16.h>

#define Bq   8
#define Tq   16
#define Nq   1024
#define Cq   48
#define Gq   32
#define Hq   150
#define H3q  450
#define TAq  32
#define OUTq 1024
#define BTq  128

#define NC_CAP 128   // active code / neighbor rows per (b,t): Binom(1024,.06) mean 61 sd 7.6
#define NM_CAP 64    // m1 / m23 rows per (b,t): Binom(1024,.03) mean 30.7 sd 5.5

__device__ __forceinline__ float lrelu(float x){ return x > 0.f ? x : 0.01f * x; }
__device__ __forceinline__ float sigm(float x){ return 1.f / (1.f + expf(-x)); }

// -------- device-global scratch (everything read is written earlier in the same call) --------
__device__ int   g_n1[BTq], g_n23[BTq], g_nchain[BTq];
__device__ short g_list1[BTq][NM_CAP];
__device__ short g_list23[BTq][NM_CAP];        // row | (m2 ? 0x400 : 0), ascending row order
__device__ short g_mapc[BTq][Nq];              // row -> slot in c-list (-1 if inactive)
__device__ short g_mapn[BTq][Nq];              // row -> slot in nb-list (-1 if inactive)
__device__ int   g_chain[BTq][NM_CAP];         // (i_slot << 16) | prev_slot for m1->m1 rows
__device__ float g_Pc[Nq][Gq];                 // c_emb @ Wg
__device__ float g_Pn[Nq][Gq];                 // n_emb @ Wg
__device__ float g_co[BTq][NC_CAP][Gq];        // co at active c rows (slot order)
__device__ float g_no[BTq][NC_CAP][Gq];        // no at active nb rows (slot order)
__device__ float g_gi[BTq][NM_CAP][H3q];       // co@Wi+bi at m1 rows (slot = list1 index)
__device__ float g_vv[BTq][NM_CAP][Hq];        // qrows@Wv+bv at m23 rows
__device__ float g_hm23[BTq][NM_CAP][Hq];      // tanh(P@v) at m23 rows (t>=1)
__device__ float g_om23[BTq][Hq];
__device__ float g_hm1[BTq][NM_CAP][Hq];       // GRU outputs at m1 rows (slot = list1 index)
__device__ float g_om1p[BTq][Hq];              // om1 max over NON-chain m1 rows
__device__ float g_outs[BTq][Hq];

// -------- K_pre: project embeddings through Wg once (linear: (adj@ce)@Wg = adj@(ce@Wg)) --------
__global__ __launch_bounds__(256) void k_pre(const float* c_emb, const float* n_emb, const float* Wg){
    int idx   = blockIdx.x * 256 + threadIdx.x;   // 65536 threads exactly
    int which = idx >> 15;
    int r     = (idx >> 5) & 1023;
    int g     = idx & 31;
    const float* emb = which ? n_emb : c_emb;
    float acc = 0.f;
    for (int c = 0; c < Cq; ++c)
        acc += emb[r * Cq + c] * Wg[c * Gq + g];
    if (which) g_Pn[r][g] = acc; else g_Pc[r][g] = acc;
}

// -------- K_co: sparse co/no at active rows only. Deterministic ballot compaction. --------
__global__ __launch_bounds__(512) void k_co(const float* code_x, const float* neighbors,
                                            const float* adj, const float* bg){
    int bt = blockIdx.x, tid = threadIdx.x;
    __shared__ short lc_s[NC_CAP], ln_s[NC_CAP];
    __shared__ int nc_s, nn_s;
    __shared__ float Pca_s[NC_CAP][Gq];   // 16 KB
    __shared__ float Pna_s[NC_CAP][Gq];   // 16 KB
    int wave = tid >> 6, lane = tid & 63;

    if (wave == 0){           // compact c-active rows (deterministic, ascending)
        int base = 0;
        for (int start = 0; start < Nq; start += 64){
            int n = start + lane;
            int pred = code_x[bt * Nq + n] > 0.f;
            unsigned long long mm = __ballot(pred);
            int pos = base + (int)__popcll(mm & ((1ull << lane) - 1ull));
            if (pred && pos < NC_CAP) lc_s[pos] = (short)n;
            base += (int)__popcll(mm);
        }
        if (lane == 0) nc_s = min(base, NC_CAP);
    } else if (wave == 1){    // compact nb-active rows
        int base = 0;
        for (int start = 0; start < Nq; start += 64){
            int n = start + lane;
            int pred = neighbors[bt * Nq + n] > 0.f;
            unsigned long long mm = __ballot(pred);
            int pos = base + (int)__popcll(mm & ((1ull << lane) - 1ull));
            if (pred && pos < NC_CAP) ln_s[pos] = (short)n;
            base += (int)__popcll(mm);
        }
        if (lane == 0) nn_s = min(base, NC_CAP);
    }
    for (int n = tid; n < Nq; n += 512){ g_mapc[bt][n] = -1; g_mapn[bt][n] = -1; }
    __syncthreads();
    int nc = nc_s, nn = nn_s;
    for (int i = tid; i < nc; i += 512) g_mapc[bt][lc_s[i]] = (short)i;
    for (int i = tid; i < nn; i += 512) g_mapn[bt][ln_s[i]] = (short)i;
    for (int idx = tid; idx < nc * Gq; idx += 512){
        int i = idx >> 5, g = idx & 31;
        Pca_s[i][g] = g_Pc[lc_s[i]][g];
    }
    for (int idx = tid; idx < nn * Gq; idx += 512){
        int i = idx >> 5, g = idx & 31;
        Pna_s[i][g] = g_Pn[ln_s[i]][g];
    }
    __syncthreads();

    int g = tid & 31;
    float bgv = bg[g];
    int total = nc + nn;
    for (int r = tid >> 5; r < total; r += 16){   // 16 groups of 32 lanes (lane = g)
        int isC = (r < nc) ? 1 : 0;
        int m = isC ? (int)lc_s[r] : (int)ln_s[r - nc];
        const float* arow = adj + (size_t)m * Nq;
        float agg = 0.f;
        #pragma unroll 4
        for (int j = 0; j < nc; ++j) agg += arow[lc_s[j]] * Pca_s[j][g];
        #pragma unroll 4
        for (int j = 0; j < nn; ++j) agg += arow[ln_s[j]] * Pna_s[j][g];
        if (isC) g_co[bt][r][g]      = lrelu(Pca_s[r][g]      + agg + bgv);
        else     g_no[bt][r - nc][g] = lrelu(Pna_s[r - nc][g] + agg + bgv);
    }
}

// -------- K_mid: lists (ballot compaction), gi at m1 rows, attention at m23 rows --------
__global__ __launch_bounds__(512) void k_mid(const float* divided, const float* u_emb,
                                             const float* Wi, const float* bi,
                                             const float* Wk, const float* bk,
                                             const float* Wq_, const float* bq_,
                                             const float* Wv_, const float* bv_,
                                             const float* bg){
    int bt = blockIdx.x, tid = threadIdx.x;
    int t = bt % Tq, btp = bt - 1;
    __shared__ short l1_s[NM_CAP], l23_s[NM_CAP];
    __shared__ int n1_s, n23_s;
    __shared__ float co1_s[NM_CAP][Gq];
    __shared__ float co23_s[NM_CAP][Gq];
    __shared__ float qr_s[NM_CAP][Gq];
    __shared__ float q_s[NM_CAP][TAq];
    __shared__ float k_s[NM_CAP][TAq];
    __shared__ float s_s[NM_CAP][NM_CAP];
    int wave = tid >> 6, lane = tid & 63;

    if (wave == 0){           // m1 list
        int base = 0;
        for (int start = 0; start < Nq; start += 64){
            int n = start + lane;
            int pred = divided[((size_t)bt * Nq + n) * 3 + 0] > 0.f;
            unsigned long long mm = __ballot(pred);
            int pos = base + (int)__popcll(mm & ((1ull << lane) - 1ull));
            if (pred && pos < NM_CAP) l1_s[pos] = (short)n;
            base += (int)__popcll(mm);
        }
        if (lane == 0) n1_s = min(base, NM_CAP);
    } else if (wave == 1){    // m23 list with m2 tag
        int base = 0;
        for (int start = 0; start < Nq; start += 64){
            int n = start + lane;
            float m2 = divided[((size_t)bt * Nq + n) * 3 + 1];
            float m3 = divided[((size_t)bt * Nq + n) * 3 + 2];
            int pred = (m2 > 0.f) || (m3 > 0.f);
            unsigned long long mm = __ballot(pred);
            int pos = base + (int)__popcll(mm & ((1ull << lane) - 1ull));
            if (pred && pos < NM_CAP) l23_s[pos] = (short)(n | (m2 > 0.f ? 0x400 : 0));
            base += (int)__popcll(mm);
        }
        if (lane == 0) n23_s = min(base, NM_CAP);
    }
    __syncthreads();
    int n1 = n1_s, n23 = n23_s;
    for (int i = tid; i < n1;  i += 512) g_list1[bt][i]  = l1_s[i];
    for (int i = tid; i < n23; i += 512) g_list23[bt][i] = l23_s[i];
    if (tid == 0){ g_n1[bt] = n1; g_n23[bt] = n23; }
    // stage co rows (m1|m2|m3 => code_x active => mapc >= 0 guaranteed)
    for (int idx = tid; idx < n1 * Gq; idx += 512){
        int i = idx >> 5, g = idx & 31;
        co1_s[i][g] = g_co[bt][g_mapc[bt][l1_s[i]]][g];
    }
    for (int idx = tid; idx < n23 * Gq; idx += 512){
        int i = idx >> 5, g = idx & 31;
        co23_s[i][g] = g_co[bt][g_mapc[bt][l23_s[i] & 1023]][g];
    }
    __syncthreads();

    // gi = co@Wi + bi at m1 rows (thread per output column, Wi column in registers)
    if (tid < H3q){
        float wcol[Gq];
        #pragma unroll
        for (int g = 0; g < Gq; ++g) wcol[g] = Wi[g * H3q + tid];
        float bij = bi[tid];
        for (int i = 0; i < n1; ++i){
            float acc = bij;
            #pragma unroll
            for (int g = 0; g < Gq; ++g) acc += co1_s[i][g] * wcol[g];
            g_gi[bt][i][tid] = acc;
        }
    }
    if (t == 0 || n23 == 0) return;   // block-uniform; attention applies only at t>=1

    // qrows: m2 -> no(t-1)[row]; inactive nb rows at t-1 have exact value lrelu(bg). m3 -> u_emb[row]
    for (int idx = tid; idx < n23 * Gq; idx += 512){
        int i = idx >> 5, g = idx & 31;
        int e = l23_s[i], row = e & 1023;
        float qv;
        if (e & 0x400){
            int slot = g_mapn[btp][row];
            qv = (slot >= 0) ? g_no[btp][slot][g] : lrelu(bg[g]);
        } else {
            qv = u_emb[row * Gq + g];
        }
        qr_s[i][g] = qv;
    }
    __syncthreads();
    // k = co@Wk+bk (keys), q = qrows@Wq+bq, v = qrows@Wv+bv
    for (int idx = tid; idx < n23 * TAq; idx += 512){
        int i = idx >> 5, a = idx & 31;
        float acck = bk[a], accq = bq_[a];
        #pragma unroll
        for (int g = 0; g < Gq; ++g){
            acck += co23_s[i][g] * Wk[g * TAq + a];
            accq += qr_s[i][g] * Wq_[g * TAq + a];
        }
        k_s[i][a] = acck; q_s[i][a] = accq;
    }
    for (int idx = tid; idx < n23 * Hq; idx += 512){
        int i = idx / Hq, h = idx % Hq;
        float acc = bv_[h];
        #pragma unroll
        for (int g = 0; g < Gq; ++g) acc += qr_s[i][g] * Wv_[g * Hq + h];
        g_vv[bt][i][h] = acc;
    }
    __syncthreads();

    const float scale = 0.17677669529663687f;   // 1/sqrt(32)
    for (int idx = tid; idx < n23 * n23; idx += 512){
        int i = idx / n23, j = idx % n23;
        float acc = 0.f;
        #pragma unroll
        for (int a = 0; a < TAq; ++a) acc += q_s[i][a] * k_s[j][a];
        s_s[i][j] = acc * scale;
    }
    __syncthreads();
    for (int i = tid; i < n23; i += 512){        // per-query softmax over the m23 key set
        float mx = -1e30f;
        for (int j = 0; j < n23; ++j) mx = fmaxf(mx, s_s[i][j]);
        float sum = 0.f;
        for (int j = 0; j < n23; ++j){ float e = expf(s_s[i][j] - mx); s_s[i][j] = e; sum += e; }
        float inv = 1.f / sum;
        for (int j = 0; j < n23; ++j) s_s[i][j] *= inv;
    }
    __syncthreads();
    for (int idx = tid; idx < n23 * Hq; idx += 512){
        int i = idx / Hq, h = idx % Hq;
        float acc = 0.f;
        for (int j = 0; j < n23; ++j) acc += s_s[i][j] * g_vv[bt][j][h];
        g_hm23[bt][i][h] = tanhf(acc);
    }
    __syncthreads();
    for (int h = tid; h < Hq; h += 512){
        float mx = -1e30f;
        for (int i = 0; i < n23; ++i) mx = fmaxf(mx, g_hm23[bt][i][h]);
        g_om23[bt][h] = mx;
    }
}

// -------- K_gru1 (parallel over all 128 (b,t)): GRU for all m1 rows EXCEPT m1->m1 chain rows.
// h_prev source per m1 row i: t==0 -> 0; m1(t-1) -> CHAIN (deferred to k_gru2);
// m23(t-1) && t>1 -> g_hm23[btp]; else 0.  Emits chain list + om1 partial max. --------
__global__ __launch_bounds__(512) void k_gru1(const float* Wh, const float* bh){
    int bt = blockIdx.x, tid = threadIdx.x;
    int t = bt % Tq, btp = bt - 1;
    __shared__ short map1p[Nq], map23p[Nq];      // 4 KB
    __shared__ short l1_s[NM_CAP];
    __shared__ unsigned char cls_s[NM_CAP];      // 0=plain, 1=chain, 2=m23-sourced
    __shared__ int m23l_s[NM_CAP];               // (i<<16)|prev_slot
    __shared__ int nf23_s;
    __shared__ float hb_s[Hq];
    __shared__ float ghf_s[H3q];
    __shared__ float hm1_s[NM_CAP][Hq];          // 38.4 KB
    int n1 = g_n1[bt];
    for (int n = tid; n < Nq; n += 512){ map1p[n] = -1; map23p[n] = -1; }
    for (int i = tid; i < n1; i += 512) l1_s[i] = g_list1[bt][i];
    __syncthreads();
    if (t >= 1){
        int n1p = g_n1[btp];
        for (int i = tid; i < n1p; i += 512) map1p[g_list1[btp][i]] = (short)i;
        if (t >= 2){
            int n23p = g_n23[btp];
            for (int i = tid; i < n23p; i += 512) map23p[g_list23[btp][i] & 1023] = (short)i;
        }
    }
    __syncthreads();
    if (tid < 64){                                // single wave: classify + ballot-compact
        int i = tid;
        int cls = 0, sp = -1;
        if (i < n1 && t >= 1){
            int row = l1_s[i];
            if (map1p[row] >= 0){ cls = 1; sp = map1p[row]; }
            else if (t >= 2 && map23p[row] >= 0){ cls = 2; sp = map23p[row]; }
        }
        if (i < n1) cls_s[i] = (unsigned char)cls;
        unsigned long long mch = __ballot(cls == 1);
        unsigned long long m23 = __ballot(cls == 2);
        int pch = (int)__popcll(mch & ((1ull << i) - 1ull));
        int p23 = (int)__popcll(m23 & ((1ull << i) - 1ull));
        if (cls == 1) g_chain[bt][pch] = (i << 16) | sp;
        if (cls == 2) m23l_s[p23] = (i << 16) | sp;
        if (i == 0){ nf23_s = (int)__popcll(m23); g_nchain[bt] = (int)__popcll(mch); }
    }
    __syncthreads();

    // plain rows: hp = 0, gh = bias only
    for (int idx = tid; idx < n1 * Hq; idx += 512){
        int i = idx / Hq, h = idx % Hq;
        if (cls_s[i] != 0) continue;
        float ir = g_gi[bt][i][h], iz = g_gi[bt][i][Hq + h], ig = g_gi[bt][i][2 * Hq + h];
        float r  = sigm(ir + bh[h]);
        float z  = sigm(iz + bh[Hq + h]);
        float ng = tanhf(ig + r * bh[2 * Hq + h]);
        hm1_s[i][h] = (1.f - z) * ng;
    }
    __syncthreads();

    // m23-sourced rows (~1 per block): full Wh matvec + GRU
    int nf23 = nf23_s;
    for (int f = 0; f < nf23; ++f){
        int pk = m23l_s[f]; int i = pk >> 16, sp = pk & 0xffff;
        for (int h = tid; h < Hq; h += 512) hb_s[h] = g_hm23[btp][sp][h];
        __syncthreads();
        for (int j = tid; j < H3q; j += 512){
            float acc = bh[j];
            for (int k2 = 0; k2 < Hq; ++k2) acc += hb_s[k2] * Wh[k2 * H3q + j];
            ghf_s[j] = acc;
        }
        __syncthreads();
        for (int h = tid; h < Hq; h += 512){
            float ir = g_gi[bt][i][h], iz = g_gi[bt][i][Hq + h], ig = g_gi[bt][i][2 * Hq + h];
            float r  = sigm(ir + ghf_s[h]);
            float z  = sigm(iz + ghf_s[Hq + h]);
            float ng = tanhf(ig + r * ghf_s[2 * Hq + h]);
            hm1_s[i][h] = (1.f - z) * ng + z * hb_s[h];
        }
        __syncthreads();
    }

    // write non-chain hm1 + om1 partial max (chain rows handled in k_gru2)
    for (int idx = tid; idx < n1 * Hq; idx += 512){
        int i = idx / Hq, h = idx % Hq;
        if (cls_s[i] != 1) g_hm1[bt][i][h] = hm1_s[i][h];
    }
    for (int h = tid; h < Hq; h += 512){
        float mx = -1e30f;
        for (int i = 0; i < n1; ++i) if (cls_s[i] != 1) mx = fmaxf(mx, hm1_s[i][h]);
        g_om1p[bt][h] = mx;
    }
}

// -------- K_gru2 (8 blocks, serial over t): only m1->m1 chain rows (~1 per step) + finalize outs --------
__global__ __launch_bounds__(512) void k_gru2(const float* Wh, const float* bh){
    int b = blockIdx.x, tid = threadIdx.x;
    __shared__ float hb_s[Hq];
    __shared__ float ghf_s[H3q];
    __shared__ float cmax_s[Hq];
    for (int t = 0; t < Tq; ++t){
        int bt = b * Tq + t, btp = bt - 1;
        int n1 = g_n1[bt], n23 = (t > 0) ? g_n23[bt] : 0;
        int nch = (t > 0) ? g_nchain[bt] : 0;
        for (int h = tid; h < Hq; h += 512) cmax_s[h] = -1e30f;
        __syncthreads();
        for (int c = 0; c < nch; ++c){
            int pk = g_chain[bt][c]; int i = pk >> 16, sp = pk & 0xffff;
            for (int h = tid; h < Hq; h += 512) hb_s[h] = g_hm1[btp][sp][h];
            __syncthreads();
            for (int j = tid; j < H3q; j += 512){
                float acc = bh[j];
                for (int k2 = 0; k2 < Hq; ++k2) acc += hb_s[k2] * Wh[k2 * H3q + j];
                ghf_s[j] = acc;
            }
            __syncthreads();
            for (int h = tid; h < Hq; h += 512){
                float ir = g_gi[bt][i][h], iz = g_gi[bt][i][Hq + h], ig = g_gi[bt][i][2 * Hq + h];
                float r  = sigm(ir + ghf_s[h]);
                float z  = sigm(iz + ghf_s[Hq + h]);
                float ng = tanhf(ig + r * ghf_s[2 * Hq + h]);
                float v  = (1.f - z) * ng + z * hb_s[h];
                g_hm1[bt][i][h] = v;
                cmax_s[h] = fmaxf(cmax_s[h], v);
            }
            __syncthreads();
        }
        // finalize outs[b,t] (thread h owns both cmax_s[h] and the write)
        for (int h = tid; h < Hq; h += 512){
            float o = 0.f;
            if (n1 > 0)  o = fmaxf(g_om1p[bt][h], cmax_s[h]);
            if (n23 > 0) o += g_om23[bt][h];
            g_outs[bt][h] = o;
        }
        __syncthreads();
    }
}

// -------- K_final: temporal attention + classifier --------
__global__ __launch_bounds__(256) void k_final(const int* lens, const float* Wd, const float* bd,
                                               const float* ctx, const float* Wc, const float* bc,
                                               float* out){
    int b = blockIdx.x, tid = threadIdx.x;
    __shared__ float outs_s[Tq][Hq];
    __shared__ float wdc_s[Hq];
    __shared__ float score_s[Tq];
    __shared__ float pooled_s[Hq];
    for (int idx = tid; idx < Tq * Hq; idx += 256){
        int t = idx / Hq, h = idx % Hq;
        outs_s[t][h] = g_outs[b * Tq + t][h];
    }
    for (int h = tid; h < Hq; h += 256){
        float acc = 0.f;
        for (int d = 0; d < 32; ++d) acc += Wd[h * 32 + d] * ctx[d];
        wdc_s[h] = acc;
    }
    __syncthreads();
    int len = lens[b];
    if (tid < Tq){
        int t = tid;
        float acc = 0.f;
        for (int d = 0; d < 32; ++d) acc += bd[d] * ctx[d];
        for (int h = 0; h < Hq; ++h) acc += outs_s[t][h] * wdc_s[h];
        score_s[t] = (t < len) ? acc : -1e30f;
    }
    __syncthreads();
    if (tid == 0){
        float mx = -1e30f;
        for (int t = 0; t < Tq; ++t) mx = fmaxf(mx, score_s[t]);
        float sum = 0.f;
        for (int t = 0; t < Tq; ++t){ float e = expf(score_s[t] - mx); score_s[t] = e; sum += e; }
        float inv = 1.f / sum;
        for (int t = 0; t < Tq; ++t) score_s[t] *= inv;
    }
    __syncthreads();
    for (int h = tid; h < Hq; h += 256){
        float acc = 0.f;
        for (int t = 0; t < Tq; ++t) acc += score_s[t] * outs_s[t][h];
        pooled_s[h] = acc;
    }
    __syncthreads();
    for (int o = tid; o < OUTq; o += 256){
        float acc = bc[o];
        for (int h = 0; h < Hq; ++h) acc += pooled_s[h] * Wc[h * OUTq + o];
        out[b * OUTq + o] = sigm(acc);
    }
}

extern "C" void kernel_launch(void* const* d_in, const int* in_sizes, int n_in,
                              void* d_out, int out_size, void* d_ws, size_t ws_size,
                              hipStream_t stream){
    const float* code_x    = (const float*)d_in[0];
    const float* divided   = (const float*)d_in[1];
    const float* neighbors = (const float*)d_in[2];
    const int*   lens      = (const int*)  d_in[3];
    const float* adj       = (const float*)d_in[4];
    const float* c_emb     = (const float*)d_in[5];
    const float* n_emb     = (const float*)d_in[6];
    const float* u_emb     = (const float*)d_in[7];
    const float* Wg        = (const float*)d_in[8];
    const float* bg        = (const float*)d_in[9];
    const float* Wi        = (const float*)d_in[10];
    const float* bi        = (const float*)d_in[11];
    const float* Wh        = (const float*)d_in[12];
    const float* bh        = (const float*)d_in[13];
    const float* Wq_       = (const float*)d_in[14];
    const float* bq_       = (const float*)d_in[15];
    const float* Wk_       = (const float*)d_in[16];
    const float* bk_       = (const float*)d_in[17];
    const float* Wv_       = (const float*)d_in[18];
    const float* bv_       = (const float*)d_in[19];
    const float* Wd_       = (const float*)d_in[20];
    const float* bd_       = (const float*)d_in[21];
    const float* ctx       = (const float*)d_in[22];
    const float* Wc_       = (const float*)d_in[23];
    const float* bc_       = (const float*)d_in[24];
    float* out = (float*)d_out;

    hipLaunchKernelGGL(k_pre,   dim3(256), dim3(256), 0, stream, c_emb, n_emb, Wg);
    hipLaunchKernelGGL(k_co,    dim3(BTq), dim3(512), 0, stream, code_x, neighbors, adj, bg);
    hipLaunchKernelGGL(k_mid,   dim3(BTq), dim3(512), 0, stream, divided, u_emb,
                       Wi, bi, Wk_, bk_, Wq_, bq_, Wv_, bv_, bg);
    hipLaunchKernelGGL(k_gru1,  dim3(BTq), dim3(512), 0, stream, Wh, bh);
    hipLaunchKernelGGL(k_gru2,  dim3(Bq),  dim3(512), 0, stream, Wh, bh);
    hipLaunchKernelGGL(k_final, dim3(Bq),  dim3(256), 0, stream, lens, Wd_, bd_, ctx, Wc_, bc_, out);
}

// Round 8
// 362.556 us; speedup vs baseline: 6.2567x; 1.2401x over previous
//
#include <hip/hip_runtime.h>
#include <hip/hip_bf16.h>

#define Bq   8
#define Tq   16
#define Nq   1024
#define Cq   48
#define Gq   32
#define Hq   150
#define H3q  450
#define TAq  32
#define OUTq 1024
#define BTq  128

#define NC_CAP 128   // active code / neighbor rows per (b,t): Binom(1024,.06) mean 61 sd 7.6
#define NM_CAP 64    // m1 / m23 rows per (b,t): Binom(1024,.03) mean 30.7 sd 5.5
#define NACT   (2 * NC_CAP)
#define MTILE  16

__device__ __forceinline__ float lrelu(float x){ return x > 0.f ? x : 0.01f * x; }
__device__ __forceinline__ float sigm(float x){ return 1.f / (1.f + expf(-x)); }

// -------- device-global scratch (everything read is written earlier in the same call) --------
__device__ int   g_n1[BTq], g_n23[BTq], g_nchain[BTq];
__device__ short g_list1[BTq][NM_CAP];
__device__ short g_list23[BTq][NM_CAP];        // row | (m2 ? 0x400 : 0), ascending row order
__device__ short g_mapc[BTq][Nq];              // row -> slot in c-list (-1 if inactive)
__device__ short g_mapn[BTq][Nq];              // row -> slot in nb-list (-1 if inactive)
__device__ int   g_chain[BTq][NM_CAP];         // (i_slot << 16) | prev_slot for m1->m1 rows
__device__ float g_Pc[Nq][Gq];                 // c_emb @ Wg
__device__ float g_Pn[Nq][Gq];                 // n_emb @ Wg
__device__ float g_co[BTq][NC_CAP][Gq];        // co at active c rows (slot order)
__device__ float g_no[BTq][NC_CAP][Gq];        // no at active nb rows (slot order)
__device__ float g_gi[BTq][NM_CAP][H3q];       // co@Wi+bi at m1 rows (slot = list1 index)
__device__ float g_vv[BTq][NM_CAP][Hq];        // qrows@Wv+bv at m23 rows
__device__ float g_hm23[BTq][NM_CAP][Hq];      // tanh(P@v) at m23 rows (t>=1)
__device__ float g_om23[BTq][Hq];
__device__ float g_hm1[BTq][NM_CAP][Hq];       // GRU outputs at m1 rows (slot = list1 index)
__device__ float g_om1p[BTq][Hq];              // om1 max over NON-chain m1 rows
__device__ float g_outs[BTq][Hq];

// -------- K_pre: project embeddings through Wg once (linear: (adj@ce)@Wg = adj@(ce@Wg)) --------
__global__ __launch_bounds__(256) void k_pre(const float* c_emb, const float* n_emb, const float* Wg){
    int idx   = blockIdx.x * 256 + threadIdx.x;   // 65536 threads exactly
    int which = idx >> 15;
    int r     = (idx >> 5) & 1023;
    int g     = idx & 31;
    const float* emb = which ? n_emb : c_emb;
    float acc = 0.f;
    for (int c = 0; c < Cq; ++c)
        acc += emb[r * Cq + c] * Wg[c * Gq + g];
    if (which) g_Pn[r][g] = acc; else g_Pc[r][g] = acc;
}

// -------- K_co: sparse co/no as tiled gathered-GEMM. 2 blocks per (b,t) (odd/even m rows). --------
// agg_m[g] = sum_j adj[m][act[j]] * Pact[j][g];  co/no[m] = lrelu(Pact[m] + agg_m + bg)
// NOTE: all __syncthreads() sit in block-uniform control flow (nc/nn/total are uniform).
__global__ __launch_bounds__(512) void k_co(const float* code_x, const float* neighbors,
                                            const float* adj, const float* bg){
    int bt = blockIdx.x >> 1, half = blockIdx.x & 1, tid = threadIdx.x;
    __shared__ short lc_s[NC_CAP], ln_s[NC_CAP];
    __shared__ short act_s[NACT];                // merged act list (c rows then nb rows)
    __shared__ int nc_s, nn_s;
    __shared__ float Pact_s[NACT][Gq];           // 32 KB
    __shared__ float A_s[MTILE][NACT];           // 16 KB
    __shared__ short mrow_s[MTILE];
    int wave = tid >> 6, lane = tid & 63;

    // phase 1: waves 0/1 compact lists; threads 128+ clear this block's map half
    if (wave == 0){           // compact c-active rows (deterministic, ascending)
        int base = 0;
        for (int start = 0; start < Nq; start += 64){
            int n = start + lane;
            int pred = code_x[bt * Nq + n] > 0.f;
            unsigned long long mm = __ballot(pred);
            int pos = base + (int)__popcll(mm & ((1ull << lane) - 1ull));
            if (pred && pos < NC_CAP) lc_s[pos] = (short)n;
            base += (int)__popcll(mm);
        }
        if (lane == 0) nc_s = min(base, NC_CAP);
    } else if (wave == 1){    // compact nb-active rows
        int base = 0;
        for (int start = 0; start < Nq; start += 64){
            int n = start + lane;
            int pred = neighbors[bt * Nq + n] > 0.f;
            unsigned long long mm = __ballot(pred);
            int pos = base + (int)__popcll(mm & ((1ull << lane) - 1ull));
            if (pred && pos < NC_CAP) ln_s[pos] = (short)n;
            base += (int)__popcll(mm);
        }
        if (lane == 0) nn_s = min(base, NC_CAP);
    } else {                  // clear map half (384 threads, 1024 entries)
        if (half == 0) for (int n = tid - 128; n < Nq; n += 384) g_mapc[bt][n] = -1;
        else           for (int n = tid - 128; n < Nq; n += 384) g_mapn[bt][n] = -1;
    }
    __syncthreads();
    int nc = nc_s, nn = nn_s, total = nc + nn;

    // phase 2: merge act list; scatter this block's map half
    for (int i = tid; i < total; i += 512) act_s[i] = (i < nc) ? lc_s[i] : ln_s[i - nc];
    if (half == 0) for (int i = tid; i < nc; i += 512) g_mapc[bt][lc_s[i]] = (short)i;
    else           for (int i = tid; i < nn; i += 512) g_mapn[bt][ln_s[i]] = (short)i;
    __syncthreads();

    // phase 3: stage Pact (reads act_s)
    for (int idx = tid; idx < total * Gq; idx += 512){
        int i = idx >> 5, g = idx & 31;
        Pact_s[i][g] = (i < nc) ? g_Pc[act_s[i]][g] : g_Pn[act_s[i]][g];
    }
    __syncthreads();

    // phase 4: my m rows are r = half, half+2, ...  (tiles of MTILE)
    int g = tid & 31, grp = tid >> 5;
    float bgv = bg[g];
    for (int rbase = half; rbase < total; rbase += 2 * MTILE){
        if (tid < MTILE){
            int r = rbase + 2 * tid;
            mrow_s[tid] = (r < total) ? act_s[r] : 0;
        }
        __syncthreads();
        int ntile = min(MTILE, (total - rbase + 1) / 2);
        // gather adj tile: ntile*total loads spread over 512 threads (independent -> latency hidden)
        for (int idx = tid; idx < ntile * total; idx += 512){
            int ti = idx / total, j = idx % total;
            A_s[ti][j] = adj[(size_t)mrow_s[ti] * Nq + act_s[j]];
        }
        __syncthreads();
        if (grp < ntile){
            int r = rbase + 2 * grp;
            float agg = 0.f;
            #pragma unroll 4
            for (int j = 0; j < total; ++j) agg += A_s[grp][j] * Pact_s[j][g];
            float v = lrelu(Pact_s[r][g] + agg + bgv);
            if (r < nc) g_co[bt][r][g]      = v;
            else        g_no[bt][r - nc][g] = v;
        }
        __syncthreads();
    }
}

// -------- K_mid: lists (ballot compaction), gi at m1 rows, attention at m23 rows --------
__global__ __launch_bounds__(512) void k_mid(const float* divided, const float* u_emb,
                                             const float* Wi, const float* bi,
                                             const float* Wk, const float* bk,
                                             const float* Wq_, const float* bq_,
                                             const float* Wv_, const float* bv_,
                                             const float* bg){
    int bt = blockIdx.x, tid = threadIdx.x;
    int t = bt % Tq, btp = bt - 1;
    __shared__ short l1_s[NM_CAP], l23_s[NM_CAP];
    __shared__ int n1_s, n23_s;
    __shared__ float co1_s[NM_CAP][Gq];
    __shared__ float co23_s[NM_CAP][Gq];
    __shared__ float qr_s[NM_CAP][Gq];
    __shared__ float q_s[NM_CAP][TAq];
    __shared__ float k_s[NM_CAP][TAq];
    __shared__ float s_s[NM_CAP][NM_CAP];
    int wave = tid >> 6, lane = tid & 63;

    if (wave == 0){           // m1 list
        int base = 0;
        for (int start = 0; start < Nq; start += 64){
            int n = start + lane;
            int pred = divided[((size_t)bt * Nq + n) * 3 + 0] > 0.f;
            unsigned long long mm = __ballot(pred);
            int pos = base + (int)__popcll(mm & ((1ull << lane) - 1ull));
            if (pred && pos < NM_CAP) l1_s[pos] = (short)n;
            base += (int)__popcll(mm);
        }
        if (lane == 0) n1_s = min(base, NM_CAP);
    } else if (wave == 1){    // m23 list with m2 tag
        int base = 0;
        for (int start = 0; start < Nq; start += 64){
            int n = start + lane;
            float m2 = divided[((size_t)bt * Nq + n) * 3 + 1];
            float m3 = divided[((size_t)bt * Nq + n) * 3 + 2];
            int pred = (m2 > 0.f) || (m3 > 0.f);
            unsigned long long mm = __ballot(pred);
            int pos = base + (int)__popcll(mm & ((1ull << lane) - 1ull));
            if (pred && pos < NM_CAP) l23_s[pos] = (short)(n | (m2 > 0.f ? 0x400 : 0));
            base += (int)__popcll(mm);
        }
        if (lane == 0) n23_s = min(base, NM_CAP);
    }
    __syncthreads();
    int n1 = n1_s, n23 = n23_s;
    for (int i = tid; i < n1;  i += 512) g_list1[bt][i]  = l1_s[i];
    for (int i = tid; i < n23; i += 512) g_list23[bt][i] = l23_s[i];
    if (tid == 0){ g_n1[bt] = n1; g_n23[bt] = n23; }
    // stage co rows (m1|m2|m3 => code_x active => mapc >= 0 guaranteed)
    for (int idx = tid; idx < n1 * Gq; idx += 512){
        int i = idx >> 5, g = idx & 31;
        co1_s[i][g] = g_co[bt][g_mapc[bt][l1_s[i]]][g];
    }
    for (int idx = tid; idx < n23 * Gq; idx += 512){
        int i = idx >> 5, g = idx & 31;
        co23_s[i][g] = g_co[bt][g_mapc[bt][l23_s[i] & 1023]][g];
    }
    __syncthreads();

    // gi = co@Wi + bi at m1 rows (thread per output column, Wi column in registers)
    if (tid < H3q){
        float wcol[Gq];
        #pragma unroll
        for (int g = 0; g < Gq; ++g) wcol[g] = Wi[g * H3q + tid];
        float bij = bi[tid];
        for (int i = 0; i < n1; ++i){
            float acc = bij;
            #pragma unroll
            for (int g = 0; g < Gq; ++g) acc += co1_s[i][g] * wcol[g];
            g_gi[bt][i][tid] = acc;
        }
    }
    if (t == 0 || n23 == 0) return;   // block-uniform; attention applies only at t>=1

    // qrows: m2 -> no(t-1)[row]; inactive nb rows at t-1 have exact value lrelu(bg). m3 -> u_emb[row]
    for (int idx = tid; idx < n23 * Gq; idx += 512){
        int i = idx >> 5, g = idx & 31;
        int e = l23_s[i], row = e & 1023;
        float qv;
        if (e & 0x400){
            int slot = g_mapn[btp][row];
            qv = (slot >= 0) ? g_no[btp][slot][g] : lrelu(bg[g]);
        } else {
            qv = u_emb[row * Gq + g];
        }
        qr_s[i][g] = qv;
    }
    __syncthreads();
    // k = co@Wk+bk (keys), q = qrows@Wq+bq, v = qrows@Wv+bv
    for (int idx = tid; idx < n23 * TAq; idx += 512){
        int i = idx >> 5, a = idx & 31;
        float acck = bk[a], accq = bq_[a];
        #pragma unroll
        for (int g = 0; g < Gq; ++g){
            acck += co23_s[i][g] * Wk[g * TAq + a];
            accq += qr_s[i][g] * Wq_[g * TAq + a];
        }
        k_s[i][a] = acck; q_s[i][a] = accq;
    }
    for (int idx = tid; idx < n23 * Hq; idx += 512){
        int i = idx / Hq, h = idx % Hq;
        float acc = bv_[h];
        #pragma unroll
        for (int g = 0; g < Gq; ++g) acc += qr_s[i][g] * Wv_[g * Hq + h];
        g_vv[bt][i][h] = acc;
    }
    __syncthreads();

    const float scale = 0.17677669529663687f;   // 1/sqrt(32)
    for (int idx = tid; idx < n23 * n23; idx += 512){
        int i = idx / n23, j = idx % n23;
        float acc = 0.f;
        #pragma unroll
        for (int a = 0; a < TAq; ++a) acc += q_s[i][a] * k_s[j][a];
        s_s[i][j] = acc * scale;
    }
    __syncthreads();
    for (int i = tid; i < n23; i += 512){        // per-query softmax over the m23 key set
        float mx = -1e30f;
        for (int j = 0; j < n23; ++j) mx = fmaxf(mx, s_s[i][j]);
        float sum = 0.f;
        for (int j = 0; j < n23; ++j){ float e = expf(s_s[i][j] - mx); s_s[i][j] = e; sum += e; }
        float inv = 1.f / sum;
        for (int j = 0; j < n23; ++j) s_s[i][j] *= inv;
    }
    __syncthreads();
    for (int idx = tid; idx < n23 * Hq; idx += 512){
        int i = idx / Hq, h = idx % Hq;
        float acc = 0.f;
        for (int j = 0; j < n23; ++j) acc += s_s[i][j] * g_vv[bt][j][h];
        g_hm23[bt][i][h] = tanhf(acc);
    }
    __syncthreads();
    for (int h = tid; h < Hq; h += 512){
        float mx = -1e30f;
        for (int i = 0; i < n23; ++i) mx = fmaxf(mx, g_hm23[bt][i][h]);
        g_om23[bt][h] = mx;
    }
}

// -------- K_gru1 (parallel over all 128 (b,t)): GRU for all m1 rows EXCEPT m1->m1 chain rows. --------
__global__ __launch_bounds__(512) void k_gru1(const float* Wh, const float* bh){
    int bt = blockIdx.x, tid = threadIdx.x;
    int t = bt % Tq, btp = bt - 1;
    __shared__ short map1p[Nq], map23p[Nq];      // 4 KB
    __shared__ short l1_s[NM_CAP];
    __shared__ unsigned char cls_s[NM_CAP];      // 0=plain, 1=chain, 2=m23-sourced
    __shared__ int m23l_s[NM_CAP];               // (i<<16)|prev_slot
    __shared__ int nf23_s;
    __shared__ float hb_s[Hq];
    __shared__ float ghf_s[H3q];
    __shared__ float hm1_s[NM_CAP][Hq];          // 38.4 KB
    int n1 = g_n1[bt];
    for (int n = tid; n < Nq; n += 512){ map1p[n] = -1; map23p[n] = -1; }
    for (int i = tid; i < n1; i += 512) l1_s[i] = g_list1[bt][i];
    __syncthreads();
    if (t >= 1){
        int n1p = g_n1[btp];
        for (int i = tid; i < n1p; i += 512) map1p[g_list1[btp][i]] = (short)i;
        if (t >= 2){
            int n23p = g_n23[btp];
            for (int i = tid; i < n23p; i += 512) map23p[g_list23[btp][i] & 1023] = (short)i;
        }
    }
    __syncthreads();
    if (tid < 64){                                // single wave: classify + ballot-compact
        int i = tid;
        int cls = 0, sp = -1;
        if (i < n1 && t >= 1){
            int row = l1_s[i];
            if (map1p[row] >= 0){ cls = 1; sp = map1p[row]; }
            else if (t >= 2 && map23p[row] >= 0){ cls = 2; sp = map23p[row]; }
        }
        if (i < n1) cls_s[i] = (unsigned char)cls;
        unsigned long long mch = __ballot(cls == 1);
        unsigned long long m23 = __ballot(cls == 2);
        int pch = (int)__popcll(mch & ((1ull << i) - 1ull));
        int p23 = (int)__popcll(m23 & ((1ull << i) - 1ull));
        if (cls == 1) g_chain[bt][pch] = (i << 16) | sp;
        if (cls == 2) m23l_s[p23] = (i << 16) | sp;
        if (i == 0){ nf23_s = (int)__popcll(m23); g_nchain[bt] = (int)__popcll(mch); }
    }
    __syncthreads();

    // plain rows: hp = 0, gh = bias only
    for (int idx = tid; idx < n1 * Hq; idx += 512){
        int i = idx / Hq, h = idx % Hq;
        if (cls_s[i] != 0) continue;
        float ir = g_gi[bt][i][h], iz = g_gi[bt][i][Hq + h], ig = g_gi[bt][i][2 * Hq + h];
        float r  = sigm(ir + bh[h]);
        float z  = sigm(iz + bh[Hq + h]);
        float ng = tanhf(ig + r * bh[2 * Hq + h]);
        hm1_s[i][h] = (1.f - z) * ng;
    }
    __syncthreads();

    // m23-sourced rows (~1 per block): full Wh matvec + GRU
    int nf23 = nf23_s;
    for (int f = 0; f < nf23; ++f){
        int pk = m23l_s[f]; int i = pk >> 16, sp = pk & 0xffff;
        for (int h = tid; h < Hq; h += 512) hb_s[h] = g_hm23[btp][sp][h];
        __syncthreads();
        for (int j = tid; j < H3q; j += 512){
            float acc = bh[j];
            for (int k2 = 0; k2 < Hq; ++k2) acc += hb_s[k2] * Wh[k2 * H3q + j];
            ghf_s[j] = acc;
        }
        __syncthreads();
        for (int h = tid; h < Hq; h += 512){
            float ir = g_gi[bt][i][h], iz = g_gi[bt][i][Hq + h], ig = g_gi[bt][i][2 * Hq + h];
            float r  = sigm(ir + ghf_s[h]);
            float z  = sigm(iz + ghf_s[Hq + h]);
            float ng = tanhf(ig + r * ghf_s[2 * Hq + h]);
            hm1_s[i][h] = (1.f - z) * ng + z * hb_s[h];
        }
        __syncthreads();
    }

    // write non-chain hm1 + om1 partial max (chain rows handled in k_gru2)
    for (int idx = tid; idx < n1 * Hq; idx += 512){
        int i = idx / Hq, h = idx % Hq;
        if (cls_s[i] != 1) g_hm1[bt][i][h] = hm1_s[i][h];
    }
    for (int h = tid; h < Hq; h += 512){
        float mx = -1e30f;
        for (int i = 0; i < n1; ++i) if (cls_s[i] != 1) mx = fmaxf(mx, hm1_s[i][h]);
        g_om1p[bt][h] = mx;
    }
}

// -------- K_gru2 (8 blocks, serial over t): only m1->m1 chain rows (~1 per step) + finalize outs --------
__global__ __launch_bounds__(512) void k_gru2(const float* Wh, const float* bh){
    int b = blockIdx.x, tid = threadIdx.x;
    __shared__ float hb_s[Hq];
    __shared__ float ghf_s[H3q];
    __shared__ float cmax_s[Hq];
    for (int t = 0; t < Tq; ++t){
        int bt = b * Tq + t, btp = bt - 1;
        int n1 = g_n1[bt], n23 = (t > 0) ? g_n23[bt] : 0;
        int nch = (t > 0) ? g_nchain[bt] : 0;
        for (int h = tid; h < Hq; h += 512) cmax_s[h] = -1e30f;
        __syncthreads();
        for (int c = 0; c < nch; ++c){
            int pk = g_chain[bt][c]; int i = pk >> 16, sp = pk & 0xffff;
            for (int h = tid; h < Hq; h += 512) hb_s[h] = g_hm1[btp][sp][h];
            __syncthreads();
            for (int j = tid; j < H3q; j += 512){
                float acc = bh[j];
                for (int k2 = 0; k2 < Hq; ++k2) acc += hb_s[k2] * Wh[k2 * H3q + j];
                ghf_s[j] = acc;
            }
            __syncthreads();
            for (int h = tid; h < Hq; h += 512){
                float ir = g_gi[bt][i][h], iz = g_gi[bt][i][Hq + h], ig = g_gi[bt][i][2 * Hq + h];
                float r  = sigm(ir + ghf_s[h]);
                float z  = sigm(iz + ghf_s[Hq + h]);
                float ng = tanhf(ig + r * ghf_s[2 * Hq + h]);
                float v  = (1.f - z) * ng + z * hb_s[h];
                g_hm1[bt][i][h] = v;
                cmax_s[h] = fmaxf(cmax_s[h], v);
            }
            __syncthreads();
        }
        // finalize outs[b,t] (thread h owns both cmax_s[h] and the write)
        for (int h = tid; h < Hq; h += 512){
            float o = 0.f;
            if (n1 > 0)  o = fmaxf(g_om1p[bt][h], cmax_s[h]);
            if (n23 > 0) o += g_om23[bt][h];
            g_outs[bt][h] = o;
        }
        __syncthreads();
    }
}

// -------- K_final: temporal attention + classifier --------
__global__ __launch_bounds__(256) void k_final(const int* lens, const float* Wd, const float* bd,
                                               const float* ctx, const float* Wc, const float* bc,
                                               float* out){
    int b = blockIdx.x, tid = threadIdx.x;
    __shared__ float outs_s[Tq][Hq];
    __shared__ float wdc_s[Hq];
    __shared__ float score_s[Tq];
    __shared__ float pooled_s[Hq];
    for (int idx = tid; idx < Tq * Hq; idx += 256){
        int t = idx / Hq, h = idx % Hq;
        outs_s[t][h] = g_outs[b * Tq + t][h];
    }
    for (int h = tid; h < Hq; h += 256){
        float acc = 0.f;
        for (int d = 0; d < 32; ++d) acc += Wd[h * 32 + d] * ctx[d];
        wdc_s[h] = acc;
    }
    __syncthreads();
    int len = lens[b];
    if (tid < Tq){
        int t = tid;
        float acc = 0.f;
        for (int d = 0; d < 32; ++d) acc += bd[d] * ctx[d];
        for (int h = 0; h < Hq; ++h) acc += outs_s[t][h] * wdc_s[h];
        score_s[t] = (t < len) ? acc : -1e30f;
    }
    __syncthreads();
    if (tid == 0){
        float mx = -1e30f;
        for (int t = 0; t < Tq; ++t) mx = fmaxf(mx, score_s[t]);
        float sum = 0.f;
        for (int t = 0; t < Tq; ++t){ float e = expf(score_s[t] - mx); score_s[t] = e; sum += e; }
        float inv = 1.f / sum;
        for (int t = 0; t < Tq; ++t) score_s[t] *= inv;
    }
    __syncthreads();
    for (int h = tid; h < Hq; h += 256){
        float acc = 0.f;
        for (int t = 0; t < Tq; ++t) acc += score_s[t] * outs_s[t][h];
        pooled_s[h] = acc;
    }
    __syncthreads();
    for (int o = tid; o < OUTq; o += 256){
        float acc = bc[o];
        for (int h = 0; h < Hq; ++h) acc += pooled_s[h] * Wc[h * OUTq + o];
        out[b * OUTq + o] = sigm(acc);
    }
}

extern "C" void kernel_launch(void* const* d_in, const int* in_sizes, int n_in,
                              void* d_out, int out_size, void* d_ws, size_t ws_size,
                              hipStream_t stream){
    const float* code_x    = (const float*)d_in[0];
    const float* divided   = (const float*)d_in[1];
    const float* neighbors = (const float*)d_in[2];
    const int*   lens      = (const int*)  d_in[3];
    const float* adj       = (const float*)d_in[4];
    const float* c_emb     = (const float*)d_in[5];
    const float* n_emb     = (const float*)d_in[6];
    const float* u_emb     = (const float*)d_in[7];
    const float* Wg        = (const float*)d_in[8];
    const float* bg        = (const float*)d_in[9];
    const float* Wi        = (const float*)d_in[10];
    const float* bi        = (const float*)d_in[11];
    const float* Wh        = (const float*)d_in[12];
    const float* bh        = (const float*)d_in[13];
    const float* Wq_       = (const float*)d_in[14];
    const float* bq_       = (const float*)d_in[15];
    const float* Wk_       = (const float*)d_in[16];
    const float* bk_       = (const float*)d_in[17];
    const float* Wv_       = (const float*)d_in[18];
    const float* bv_       = (const float*)d_in[19];
    const float* Wd_       = (const float*)d_in[20];
    const float* bd_       = (const float*)d_in[21];
    const float* ctx       = (const float*)d_in[22];
    const float* Wc_       = (const float*)d_in[23];
    const float* bc_       = (const float*)d_in[24];
    float* out = (float*)d_out;

    hipLaunchKernelGGL(k_pre,   dim3(256),     dim3(256), 0, stream, c_emb, n_emb, Wg);
    hipLaunchKernelGGL(k_co,    dim3(2 * BTq), dim3(512), 0, stream, code_x, neighbors, adj, bg);
    hipLaunchKernelGGL(k_mid,   dim3(BTq),     dim3(512), 0, stream, divided, u_emb,
                       Wi, bi, Wk_, bk_, Wq_, bq_, Wv_, bv_, bg);
    hipLaunchKernelGGL(k_gru1,  dim3(BTq),     dim3(512), 0, stream, Wh, bh);
    hipLaunchKernelGGL(k_gru2,  dim3(Bq),      dim3(512), 0, stream, Wh, bh);
    hipLaunchKernelGGL(k_final, dim3(Bq),      dim3(256), 0, stream, lens, Wd_, bd_, ctx, Wc_, bc_, out);
}

// Round 9
// 287.147 us; speedup vs baseline: 7.8998x; 1.2626x over previous
//
#include <hip/hip_runtime.h>
#include <hip/hip_bf16.h>

#define Bq   8
#define Tq   16
#define Nq   1024
#define Cq   48
#define Gq   32
#define Hq   150
#define H3q  450
#define TAq  32
#define OUTq 1024
#define BTq  128

#define NC_CAP 128   // active code / neighbor rows per (b,t): Binom(1024,.06) mean 61 sd 7.6
#define NM_CAP 64    // m1 / m23 rows per (b,t): Binom(1024,.03) mean 30.7 sd 5.5
#define NACT   (2 * NC_CAP)
#define MTILE  16

__device__ __forceinline__ float lrelu(float x){ return x > 0.f ? x : 0.01f * x; }
__device__ __forceinline__ float sigm(float x){ return 1.f / (1.f + expf(-x)); }

// -------- device-global scratch (everything read is written earlier in the same call) --------
__device__ int   g_n1[BTq], g_n23[BTq], g_nchain[BTq], g_nchain2[BTq];
__device__ short g_list1[BTq][NM_CAP];
__device__ short g_list23[BTq][NM_CAP];        // row | (m2 ? 0x400 : 0), ascending row order
__device__ short g_mapc[BTq][Nq];              // row -> slot in c-list (-1 if inactive)
__device__ short g_mapn[BTq][Nq];              // row -> slot in nb-list (-1 if inactive)
__device__ int   g_chain[BTq][NM_CAP];         // (i_slot << 16) | prev_slot for m1->m1 rows
__device__ int   g_chain2[BTq][NM_CAP];        // deep-chain subset (source itself chain at t-1)
__device__ unsigned char g_cls[BTq][NM_CAP];   // per-m1-row class: 0 plain, 1 chain, 2 m23-sourced
__device__ float g_Pc[Nq][Gq];                 // c_emb @ Wg
__device__ float g_Pn[Nq][Gq];                 // n_emb @ Wg
__device__ float g_co[BTq][NC_CAP][Gq];        // co at active c rows (slot order)
__device__ float g_no[BTq][NC_CAP][Gq];        // no at active nb rows (slot order)
__device__ float g_gi[BTq][NM_CAP][H3q];       // co@Wi+bi at m1 rows (slot = list1 index)
__device__ float g_vv[BTq][NM_CAP][Hq];        // qrows@Wv+bv at m23 rows
__device__ float g_hm23[BTq][NM_CAP][Hq];      // tanh(P@v) at m23 rows (t>=1)
__device__ float g_om23[BTq][Hq];
__device__ float g_hm1[BTq][NM_CAP][Hq];       // GRU outputs at m1 rows (slot = list1 index)
__device__ float g_om1p[BTq][Hq];              // om1 max over NON-chain m1 rows
__device__ float g_om1c[BTq][Hq];              // om1 max over depth-1 chain rows (k_gru1b)
__device__ float g_outs_unused[1];

// -------- K_pre: project embeddings through Wg once (linear: (adj@ce)@Wg = adj@(ce@Wg)) --------
__global__ __launch_bounds__(256) void k_pre(const float* c_emb, const float* n_emb, const float* Wg){
    int idx   = blockIdx.x * 256 + threadIdx.x;   // 65536 threads exactly
    int which = idx >> 15;
    int r     = (idx >> 5) & 1023;
    int g     = idx & 31;
    const float* emb = which ? n_emb : c_emb;
    float acc = 0.f;
    for (int c = 0; c < Cq; ++c)
        acc += emb[r * Cq + c] * Wg[c * Gq + g];
    if (which) g_Pn[r][g] = acc; else g_Pc[r][g] = acc;
}

// -------- K_co: sparse co/no as tiled gathered-GEMM. 2 blocks per (b,t) (odd/even m rows). --------
__global__ __launch_bounds__(512) void k_co(const float* code_x, const float* neighbors,
                                            const float* adj, const float* bg){
    int bt = blockIdx.x >> 1, half = blockIdx.x & 1, tid = threadIdx.x;
    __shared__ short lc_s[NC_CAP], ln_s[NC_CAP];
    __shared__ short act_s[NACT];
    __shared__ int nc_s, nn_s;
    __shared__ float Pact_s[NACT][Gq];           // 32 KB
    __shared__ float A_s[MTILE][NACT];           // 16 KB
    __shared__ short mrow_s[MTILE];
    int wave = tid >> 6, lane = tid & 63;

    if (wave == 0){           // compact c-active rows (deterministic, ascending)
        int base = 0;
        for (int start = 0; start < Nq; start += 64){
            int n = start + lane;
            int pred = code_x[bt * Nq + n] > 0.f;
            unsigned long long mm = __ballot(pred);
            int pos = base + (int)__popcll(mm & ((1ull << lane) - 1ull));
            if (pred && pos < NC_CAP) lc_s[pos] = (short)n;
            base += (int)__popcll(mm);
        }
        if (lane == 0) nc_s = min(base, NC_CAP);
    } else if (wave == 1){    // compact nb-active rows
        int base = 0;
        for (int start = 0; start < Nq; start += 64){
            int n = start + lane;
            int pred = neighbors[bt * Nq + n] > 0.f;
            unsigned long long mm = __ballot(pred);
            int pos = base + (int)__popcll(mm & ((1ull << lane) - 1ull));
            if (pred && pos < NC_CAP) ln_s[pos] = (short)n;
            base += (int)__popcll(mm);
        }
        if (lane == 0) nn_s = min(base, NC_CAP);
    } else {                  // clear map half (384 threads, 1024 entries)
        if (half == 0) for (int n = tid - 128; n < Nq; n += 384) g_mapc[bt][n] = -1;
        else           for (int n = tid - 128; n < Nq; n += 384) g_mapn[bt][n] = -1;
    }
    __syncthreads();
    int nc = nc_s, nn = nn_s, total = nc + nn;

    for (int i = tid; i < total; i += 512) act_s[i] = (i < nc) ? lc_s[i] : ln_s[i - nc];
    if (half == 0) for (int i = tid; i < nc; i += 512) g_mapc[bt][lc_s[i]] = (short)i;
    else           for (int i = tid; i < nn; i += 512) g_mapn[bt][ln_s[i]] = (short)i;
    __syncthreads();

    for (int idx = tid; idx < total * Gq; idx += 512){
        int i = idx >> 5, g = idx & 31;
        Pact_s[i][g] = (i < nc) ? g_Pc[act_s[i]][g] : g_Pn[act_s[i]][g];
    }
    __syncthreads();

    int g = tid & 31, grp = tid >> 5;
    float bgv = bg[g];
    for (int rbase = half; rbase < total; rbase += 2 * MTILE){
        if (tid < MTILE){
            int r = rbase + 2 * tid;
            mrow_s[tid] = (r < total) ? act_s[r] : 0;
        }
        __syncthreads();
        int ntile = min(MTILE, (total - rbase + 1) / 2);
        for (int idx = tid; idx < ntile * total; idx += 512){
            int ti = idx / total, j = idx % total;
            A_s[ti][j] = adj[(size_t)mrow_s[ti] * Nq + act_s[j]];
        }
        __syncthreads();
        if (grp < ntile){
            int r = rbase + 2 * grp;
            float agg = 0.f;
            #pragma unroll 4
            for (int j = 0; j < total; ++j) agg += A_s[grp][j] * Pact_s[j][g];
            float v = lrelu(Pact_s[r][g] + agg + bgv);
            if (r < nc) g_co[bt][r][g]      = v;
            else        g_no[bt][r - nc][g] = v;
        }
        __syncthreads();
    }
}

// -------- K_mid: lists (ballot compaction), gi at m1 rows, attention at m23 rows --------
__global__ __launch_bounds__(512) void k_mid(const float* divided, const float* u_emb,
                                             const float* Wi, const float* bi,
                                             const float* Wk, const float* bk,
                                             const float* Wq_, const float* bq_,
                                             const float* Wv_, const float* bv_,
                                             const float* bg){
    int bt = blockIdx.x, tid = threadIdx.x;
    int t = bt % Tq, btp = bt - 1;
    __shared__ short l1_s[NM_CAP], l23_s[NM_CAP];
    __shared__ int n1_s, n23_s;
    __shared__ float co1_s[NM_CAP][Gq];
    __shared__ float co23_s[NM_CAP][Gq];
    __shared__ float qr_s[NM_CAP][Gq];
    __shared__ float q_s[NM_CAP][TAq];
    __shared__ float k_s[NM_CAP][TAq];
    __shared__ float s_s[NM_CAP][NM_CAP];
    int wave = tid >> 6, lane = tid & 63;

    if (wave == 0){           // m1 list
        int base = 0;
        for (int start = 0; start < Nq; start += 64){
            int n = start + lane;
            int pred = divided[((size_t)bt * Nq + n) * 3 + 0] > 0.f;
            unsigned long long mm = __ballot(pred);
            int pos = base + (int)__popcll(mm & ((1ull << lane) - 1ull));
            if (pred && pos < NM_CAP) l1_s[pos] = (short)n;
            base += (int)__popcll(mm);
        }
        if (lane == 0) n1_s = min(base, NM_CAP);
    } else if (wave == 1){    // m23 list with m2 tag
        int base = 0;
        for (int start = 0; start < Nq; start += 64){
            int n = start + lane;
            float m2 = divided[((size_t)bt * Nq + n) * 3 + 1];
            float m3 = divided[((size_t)bt * Nq + n) * 3 + 2];
            int pred = (m2 > 0.f) || (m3 > 0.f);
            unsigned long long mm = __ballot(pred);
            int pos = base + (int)__popcll(mm & ((1ull << lane) - 1ull));
            if (pred && pos < NM_CAP) l23_s[pos] = (short)(n | (m2 > 0.f ? 0x400 : 0));
            base += (int)__popcll(mm);
        }
        if (lane == 0) n23_s = min(base, NM_CAP);
    }
    __syncthreads();
    int n1 = n1_s, n23 = n23_s;
    for (int i = tid; i < n1;  i += 512) g_list1[bt][i]  = l1_s[i];
    for (int i = tid; i < n23; i += 512) g_list23[bt][i] = l23_s[i];
    if (tid == 0){ g_n1[bt] = n1; g_n23[bt] = n23; }
    for (int idx = tid; idx < n1 * Gq; idx += 512){
        int i = idx >> 5, g = idx & 31;
        co1_s[i][g] = g_co[bt][g_mapc[bt][l1_s[i]]][g];
    }
    for (int idx = tid; idx < n23 * Gq; idx += 512){
        int i = idx >> 5, g = idx & 31;
        co23_s[i][g] = g_co[bt][g_mapc[bt][l23_s[i] & 1023]][g];
    }
    __syncthreads();

    // gi = co@Wi + bi at m1 rows (thread per output column, Wi column in registers)
    if (tid < H3q){
        float wcol[Gq];
        #pragma unroll
        for (int g = 0; g < Gq; ++g) wcol[g] = Wi[g * H3q + tid];
        float bij = bi[tid];
        for (int i = 0; i < n1; ++i){
            float acc = bij;
            #pragma unroll
            for (int g = 0; g < Gq; ++g) acc += co1_s[i][g] * wcol[g];
            g_gi[bt][i][tid] = acc;
        }
    }
    if (t == 0 || n23 == 0) return;   // block-uniform; attention applies only at t>=1

    for (int idx = tid; idx < n23 * Gq; idx += 512){
        int i = idx >> 5, g = idx & 31;
        int e = l23_s[i], row = e & 1023;
        float qv;
        if (e & 0x400){
            int slot = g_mapn[btp][row];
            qv = (slot >= 0) ? g_no[btp][slot][g] : lrelu(bg[g]);
        } else {
            qv = u_emb[row * Gq + g];
        }
        qr_s[i][g] = qv;
    }
    __syncthreads();
    for (int idx = tid; idx < n23 * TAq; idx += 512){
        int i = idx >> 5, a = idx & 31;
        float acck = bk[a], accq = bq_[a];
        #pragma unroll
        for (int g = 0; g < Gq; ++g){
            acck += co23_s[i][g] * Wk[g * TAq + a];
            accq += qr_s[i][g] * Wq_[g * TAq + a];
        }
        k_s[i][a] = acck; q_s[i][a] = accq;
    }
    for (int idx = tid; idx < n23 * Hq; idx += 512){
        int i = idx / Hq, h = idx % Hq;
        float acc = bv_[h];
        #pragma unroll
        for (int g = 0; g < Gq; ++g) acc += qr_s[i][g] * Wv_[g * Hq + h];
        g_vv[bt][i][h] = acc;
    }
    __syncthreads();

    const float scale = 0.17677669529663687f;   // 1/sqrt(32)
    for (int idx = tid; idx < n23 * n23; idx += 512){
        int i = idx / n23, j = idx % n23;
        float acc = 0.f;
        #pragma unroll
        for (int a = 0; a < TAq; ++a) acc += q_s[i][a] * k_s[j][a];
        s_s[i][j] = acc * scale;
    }
    __syncthreads();
    for (int i = tid; i < n23; i += 512){        // per-query softmax over the m23 key set
        float mx = -1e30f;
        for (int j = 0; j < n23; ++j) mx = fmaxf(mx, s_s[i][j]);
        float sum = 0.f;
        for (int j = 0; j < n23; ++j){ float e = expf(s_s[i][j] - mx); s_s[i][j] = e; sum += e; }
        float inv = 1.f / sum;
        for (int j = 0; j < n23; ++j) s_s[i][j] *= inv;
    }
    __syncthreads();
    for (int idx = tid; idx < n23 * Hq; idx += 512){
        int i = idx / Hq, h = idx % Hq;
        float acc = 0.f;
        for (int j = 0; j < n23; ++j) acc += s_s[i][j] * g_vv[bt][j][h];
        g_hm23[bt][i][h] = tanhf(acc);
    }
    __syncthreads();
    for (int h = tid; h < Hq; h += 512){
        float mx = -1e30f;
        for (int i = 0; i < n23; ++i) mx = fmaxf(mx, g_hm23[bt][i][h]);
        g_om23[bt][h] = mx;
    }
}

// -------- K_gru1 (parallel): GRU for plain + m23-sourced m1 rows; emits chain list + cls --------
__global__ __launch_bounds__(512) void k_gru1(const float* Wh, const float* bh){
    int bt = blockIdx.x, tid = threadIdx.x;
    int t = bt % Tq, btp = bt - 1;
    __shared__ short map1p[Nq], map23p[Nq];      // 4 KB
    __shared__ short l1_s[NM_CAP];
    __shared__ unsigned char cls_s[NM_CAP];      // 0=plain, 1=chain, 2=m23-sourced
    __shared__ int m23l_s[NM_CAP];               // (i<<16)|prev_slot
    __shared__ int nf23_s;
    __shared__ float hb_s[Hq];
    __shared__ float ghf_s[H3q];
    __shared__ float hm1_s[NM_CAP][Hq];          // 38.4 KB
    int n1 = g_n1[bt];
    for (int n = tid; n < Nq; n += 512){ map1p[n] = -1; map23p[n] = -1; }
    for (int i = tid; i < n1; i += 512) l1_s[i] = g_list1[bt][i];
    __syncthreads();
    if (t >= 1){
        int n1p = g_n1[btp];
        for (int i = tid; i < n1p; i += 512) map1p[g_list1[btp][i]] = (short)i;
        if (t >= 2){
            int n23p = g_n23[btp];
            for (int i = tid; i < n23p; i += 512) map23p[g_list23[btp][i] & 1023] = (short)i;
        }
    }
    __syncthreads();
    if (tid < 64){                                // single wave: classify + ballot-compact
        int i = tid;
        int cls = 0, sp = -1;
        if (i < n1 && t >= 1){
            int row = l1_s[i];
            if (map1p[row] >= 0){ cls = 1; sp = map1p[row]; }
            else if (t >= 2 && map23p[row] >= 0){ cls = 2; sp = map23p[row]; }
        }
        if (i < n1){ cls_s[i] = (unsigned char)cls; g_cls[bt][i] = (unsigned char)cls; }
        unsigned long long mch = __ballot(cls == 1);
        unsigned long long m23 = __ballot(cls == 2);
        int pch = (int)__popcll(mch & ((1ull << i) - 1ull));
        int p23 = (int)__popcll(m23 & ((1ull << i) - 1ull));
        if (cls == 1) g_chain[bt][pch] = (i << 16) | sp;
        if (cls == 2) m23l_s[p23] = (i << 16) | sp;
        if (i == 0){ nf23_s = (int)__popcll(m23); g_nchain[bt] = (int)__popcll(mch); }
    }
    __syncthreads();

    // plain rows: hp = 0, gh = bias only
    for (int idx = tid; idx < n1 * Hq; idx += 512){
        int i = idx / Hq, h = idx % Hq;
        if (cls_s[i] != 0) continue;
        float ir = g_gi[bt][i][h], iz = g_gi[bt][i][Hq + h], ig = g_gi[bt][i][2 * Hq + h];
        float r  = sigm(ir + bh[h]);
        float z  = sigm(iz + bh[Hq + h]);
        float ng = tanhf(ig + r * bh[2 * Hq + h]);
        hm1_s[i][h] = (1.f - z) * ng;
    }
    __syncthreads();

    // m23-sourced rows (~1 per block): full Wh matvec + GRU
    int nf23 = nf23_s;
    for (int f = 0; f < nf23; ++f){
        int pk = m23l_s[f]; int i = pk >> 16, sp = pk & 0xffff;
        for (int h = tid; h < Hq; h += 512) hb_s[h] = g_hm23[btp][sp][h];
        __syncthreads();
        for (int j = tid; j < H3q; j += 512){
            float acc = bh[j];
            for (int k2 = 0; k2 < Hq; ++k2) acc += hb_s[k2] * Wh[k2 * H3q + j];
            ghf_s[j] = acc;
        }
        __syncthreads();
        for (int h = tid; h < Hq; h += 512){
            float ir = g_gi[bt][i][h], iz = g_gi[bt][i][Hq + h], ig = g_gi[bt][i][2 * Hq + h];
            float r  = sigm(ir + ghf_s[h]);
            float z  = sigm(iz + ghf_s[Hq + h]);
            float ng = tanhf(ig + r * ghf_s[2 * Hq + h]);
            hm1_s[i][h] = (1.f - z) * ng + z * hb_s[h];
        }
        __syncthreads();
    }

    // write non-chain hm1 + om1 partial max (chain rows: k_gru1b / k_gru2)
    for (int idx = tid; idx < n1 * Hq; idx += 512){
        int i = idx / Hq, h = idx % Hq;
        if (cls_s[i] != 1) g_hm1[bt][i][h] = hm1_s[i][h];
    }
    for (int h = tid; h < Hq; h += 512){
        float mx = -1e30f;
        for (int i = 0; i < n1; ++i) if (cls_s[i] != 1) mx = fmaxf(mx, hm1_s[i][h]);
        g_om1p[bt][h] = mx;
    }
}

// -------- K_gru1b (parallel): depth-1 chain rows (source non-chain at t-1, final after k_gru1).
// Deep-chain rows (source itself chain) are ballot-compacted into g_chain2 for k_gru2. --------
__global__ __launch_bounds__(512) void k_gru1b(const float* Wh, const float* bh){
    int bt = blockIdx.x, tid = threadIdx.x;
    int t = bt % Tq, btp = bt - 1;
    __shared__ unsigned char defer_s[NM_CAP];
    __shared__ float hb_s[Hq];
    __shared__ float ghf_s[H3q];
    __shared__ float cmax_s[Hq];
    int nch = (t > 0) ? g_nchain[bt] : 0;
    for (int h = tid; h < Hq; h += 512) cmax_s[h] = -1e30f;
    if (tid < 64){
        int c = tid;
        int defer = 0;
        if (c < nch){
            int sp = g_chain[bt][c] & 0xffff;
            defer = (g_cls[btp][sp] == 1) ? 1 : 0;   // source is chain at t-1 -> defer
            defer_s[c] = (unsigned char)defer;
        }
        unsigned long long md = __ballot((c < nch) && defer);
        int pos = (int)__popcll(md & ((1ull << c) - 1ull));
        if ((c < nch) && defer) g_chain2[bt][pos] = g_chain[bt][c];
        if (c == 0) g_nchain2[bt] = (int)__popcll(md);
    }
    __syncthreads();
    for (int c = 0; c < nch; ++c){
        if (defer_s[c]) continue;                    // block-uniform
        int pk = g_chain[bt][c]; int i = pk >> 16, sp = pk & 0xffff;
        for (int h = tid; h < Hq; h += 512) hb_s[h] = g_hm1[btp][sp][h];
        __syncthreads();
        for (int j = tid; j < H3q; j += 512){
            float acc = bh[j];
            for (int k2 = 0; k2 < Hq; ++k2) acc += hb_s[k2] * Wh[k2 * H3q + j];
            ghf_s[j] = acc;
        }
        __syncthreads();
        for (int h = tid; h < Hq; h += 512){
            float ir = g_gi[bt][i][h], iz = g_gi[bt][i][Hq + h], ig = g_gi[bt][i][2 * Hq + h];
            float r  = sigm(ir + ghf_s[h]);
            float z  = sigm(iz + ghf_s[Hq + h]);
            float ng = tanhf(ig + r * ghf_s[2 * Hq + h]);
            float v  = (1.f - z) * ng + z * hb_s[h];
            g_hm1[bt][i][h] = v;
            cmax_s[h] = fmaxf(cmax_s[h], v);
        }
        __syncthreads();
    }
    for (int h = tid; h < Hq; h += 512) g_om1c[bt][h] = cmax_s[h];
}

// -------- K_gru2 (8 blocks, serial over t): ONLY deep-chain rows (~3 in the whole problem) --------
__global__ __launch_bounds__(512) void k_gru2(const float* Wh, const float* bh){
    int b = blockIdx.x, tid = threadIdx.x;
    __shared__ float hb_s[Hq];
    __shared__ float ghf_s[H3q];
    for (int t = 1; t < Tq; ++t){
        int bt = b * Tq + t, btp = bt - 1;
        int nch2 = g_nchain2[bt];
        for (int c = 0; c < nch2; ++c){
            int pk = g_chain2[bt][c]; int i = pk >> 16, sp = pk & 0xffff;
            for (int h = tid; h < Hq; h += 512) hb_s[h] = g_hm1[btp][sp][h];
            __syncthreads();
            for (int j = tid; j < H3q; j += 512){
                float acc = bh[j];
                for (int k2 = 0; k2 < Hq; ++k2) acc += hb_s[k2] * Wh[k2 * H3q + j];
                ghf_s[j] = acc;
            }
            __syncthreads();
            for (int h = tid; h < Hq; h += 512){
                float ir = g_gi[bt][i][h], iz = g_gi[bt][i][Hq + h], ig = g_gi[bt][i][2 * Hq + h];
                float r  = sigm(ir + ghf_s[h]);
                float z  = sigm(iz + ghf_s[Hq + h]);
                float ng = tanhf(ig + r * ghf_s[2 * Hq + h]);
                g_hm1[bt][i][h] = (1.f - z) * ng + z * hb_s[h];
            }
            __syncthreads();
        }
    }
}

// -------- K_final: finalize outs (om1p/om1c/deferred + om23), temporal attention + classifier --------
__global__ __launch_bounds__(256) void k_final(const int* lens, const float* Wd, const float* bd,
                                               const float* ctx, const float* Wc, const float* bc,
                                               float* out){
    int b = blockIdx.x, tid = threadIdx.x;
    __shared__ float outs_s[Tq][Hq];
    __shared__ float wdc_s[Hq];
    __shared__ float score_s[Tq];
    __shared__ float pooled_s[Hq];
    for (int idx = tid; idx < Tq * Hq; idx += 256){
        int t = idx / Hq, h = idx % Hq;
        int bt = b * Tq + t;
        int n1 = g_n1[bt], n23 = (t > 0) ? g_n23[bt] : 0;
        float o = 0.f;
        if (n1 > 0){
            float mx = fmaxf(g_om1p[bt][h], g_om1c[bt][h]);
            int nd = (t > 0) ? g_nchain2[bt] : 0;
            for (int c = 0; c < nd; ++c){
                int i = g_chain2[bt][c] >> 16;
                mx = fmaxf(mx, g_hm1[bt][i][h]);
            }
            o = mx;
        }
        if (n23 > 0) o += g_om23[bt][h];
        outs_s[t][h] = o;
    }
    for (int h = tid; h < Hq; h += 256){
        float acc = 0.f;
        for (int d = 0; d < 32; ++d) acc += Wd[h * 32 + d] * ctx[d];
        wdc_s[h] = acc;
    }
    __syncthreads();
    int len = lens[b];
    if (tid < Tq){
        int t = tid;
        float acc = 0.f;
        for (int d = 0; d < 32; ++d) acc += bd[d] * ctx[d];
        for (int h = 0; h < Hq; ++h) acc += outs_s[t][h] * wdc_s[h];
        score_s[t] = (t < len) ? acc : -1e30f;
    }
    __syncthreads();
    if (tid == 0){
        float mx = -1e30f;
        for (int t = 0; t < Tq; ++t) mx = fmaxf(mx, score_s[t]);
        float sum = 0.f;
        for (int t = 0; t < Tq; ++t){ float e = expf(score_s[t] - mx); score_s[t] = e; sum += e; }
        float inv = 1.f / sum;
        for (int t = 0; t < Tq; ++t) score_s[t] *= inv;
    }
    __syncthreads();
    for (int h = tid; h < Hq; h += 256){
        float acc = 0.f;
        for (int t = 0; t < Tq; ++t) acc += score_s[t] * outs_s[t][h];
        pooled_s[h] = acc;
    }
    __syncthreads();
    for (int o = tid; o < OUTq; o += 256){
        float acc = bc[o];
        for (int h = 0; h < Hq; ++h) acc += pooled_s[h] * Wc[h * OUTq + o];
        out[b * OUTq + o] = sigm(acc);
    }
}

extern "C" void kernel_launch(void* const* d_in, const int* in_sizes, int n_in,
                              void* d_out, int out_size, void* d_ws, size_t ws_size,
                              hipStream_t stream){
    const float* code_x    = (const float*)d_in[0];
    const float* divided   = (const float*)d_in[1];
    const float* neighbors = (const float*)d_in[2];
    const int*   lens      = (const int*)  d_in[3];
    const float* adj       = (const float*)d_in[4];
    const float* c_emb     = (const float*)d_in[5];
    const float* n_emb     = (const float*)d_in[6];
    const float* u_emb     = (const float*)d_in[7];
    const float* Wg        = (const float*)d_in[8];
    const float* bg        = (const float*)d_in[9];
    const float* Wi        = (const float*)d_in[10];
    const float* bi        = (const float*)d_in[11];
    const float* Wh        = (const float*)d_in[12];
    const float* bh        = (const float*)d_in[13];
    const float* Wq_       = (const float*)d_in[14];
    const float* bq_       = (const float*)d_in[15];
    const float* Wk_       = (const float*)d_in[16];
    const float* bk_       = (const float*)d_in[17];
    const float* Wv_       = (const float*)d_in[18];
    const float* bv_       = (const float*)d_in[19];
    const float* Wd_       = (const float*)d_in[20];
    const float* bd_       = (const float*)d_in[21];
    const float* ctx       = (const float*)d_in[22];
    const float* Wc_       = (const float*)d_in[23];
    const float* bc_       = (const float*)d_in[24];
    float* out = (float*)d_out;

    hipLaunchKernelGGL(k_pre,   dim3(256),     dim3(256), 0, stream, c_emb, n_emb, Wg);
    hipLaunchKernelGGL(k_co,    dim3(2 * BTq), dim3(512), 0, stream, code_x, neighbors, adj, bg);
    hipLaunchKernelGGL(k_mid,   dim3(BTq),     dim3(512), 0, stream, divided, u_emb,
                       Wi, bi, Wk_, bk_, Wq_, bq_, Wv_, bv_, bg);
    hipLaunchKernelGGL(k_gru1,  dim3(BTq),     dim3(512), 0, stream, Wh, bh);
    hipLaunchKernelGGL(k_gru1b, dim3(BTq),     dim3(512), 0, stream, Wh, bh);
    hipLaunchKernelGGL(k_gru2,  dim3(Bq),      dim3(512), 0, stream, Wh, bh);
    hipLaunchKernelGGL(k_final, dim3(Bq),      dim3(256), 0, stream, lens, Wd_, bd_, ctx, Wc_, bc_, out);
}